// Round 7
// baseline (942.852 us; speedup 1.0000x reference)
//
#include <hip/hip_runtime.h>

typedef __attribute__((ext_vector_type(8))) short bf16x8;
typedef __attribute__((ext_vector_type(4))) float f32x4;
typedef __attribute__((ext_vector_type(16))) float f32x16;

__device__ __forceinline__ float b2f(short s) {
  return __uint_as_float(((unsigned int)(unsigned short)s) << 16);
}
__device__ __forceinline__ short f2b(float f) {
  unsigned int u = __float_as_uint(f);
  unsigned int r = (u + 0x7fffu + ((u >> 16) & 1u)) >> 16;
  return (short)(unsigned short)r;
}

#define GLOAD16(g, l) __builtin_amdgcn_global_load_lds( \
    (const __attribute__((address_space(1))) void*)(g),  \
    (__attribute__((address_space(3))) void*)(l), 16, 0, 0)

// ---------------- f32 -> bf16 convert ----------------
__global__ __launch_bounds__(256) void cvt_kernel(const float* __restrict__ src,
                                                  short* __restrict__ dst, long n) {
  long i = ((long)blockIdx.x * 256 + threadIdx.x) * 8;
  long stride = (long)gridDim.x * 256 * 8;
  for (; i + 8 <= n; i += stride) {
    float4 a = *(const float4*)(src + i);
    float4 b = *(const float4*)(src + i + 4);
    bf16x8 o;
    o[0] = f2b(a.x); o[1] = f2b(a.y); o[2] = f2b(a.z); o[3] = f2b(a.w);
    o[4] = f2b(b.x); o[5] = f2b(b.y); o[6] = f2b(b.z); o[7] = f2b(b.w);
    *(bf16x8*)(dst + i) = o;
  }
}

// ---------------- gather next-token embeddings, shift, convert ----------------
__global__ __launch_bounds__(256) void gather_kernel(const float* __restrict__ emb,
    const int* __restrict__ ids, short* __restrict__ sh) {
  const int token = blockIdx.x;          // 0..4095, token = b*2048 + s
  const int s = token & 2047;
  const long dst = (long)token * 4096;
  const int row = (s == 2047) ? -1 : ids[token + 1];
  for (int it = 0; it < 2; ++it) {
    const int e = it * 2048 + threadIdx.x * 8;
    bf16x8 o;
    if (row < 0) {
      #pragma unroll
      for (int j = 0; j < 8; ++j) o[j] = 0;
    } else {
      float4 a = *(const float4*)(emb + (long)row * 4096 + e);
      float4 b = *(const float4*)(emb + (long)row * 4096 + e + 4);
      o[0] = f2b(a.x); o[1] = f2b(a.y); o[2] = f2b(a.z); o[3] = f2b(a.w);
      o[4] = f2b(b.x); o[5] = f2b(b.y); o[6] = f2b(b.z); o[7] = f2b(b.w);
    }
    *(bf16x8*)(sh + dst + e) = o;
  }
}

// ---------------- init_A [4096][16] f32 -> [16][4096] bf16 ----------------
__global__ __launch_bounds__(256) void tposeA_kernel(const float* __restrict__ A,
                                                     short* __restrict__ At) {
  const int h = blockIdx.x * 256 + threadIdx.x;
  #pragma unroll
  for (int r = 0; r < 16; ++r) At[(long)r * 4096 + h] = f2b(A[(long)h * 16 + r]);
}

// ======== deep-pipelined 256x256 MFMA GEMM: C[M,N] = A[M,K] @ B[N,K]^T ========
// Round-7: 32x32x16 MFMA (2495 TF ceiling vs 2075 for 16x16). Same staging,
// same 4-phase/8-barrier schedule, same counted vmcnt(6)/lgkmcnt(4) waits as
// the verified r5/r6 kernel. Operand map: A/B lane holds row/col=lane&31,
// k-granule kc = s*2 + (lane>>5); C: col=lane&31, row=(reg&3)+8*(reg>>2)+
// 4*(lane>>5) [m74/m101]. LDS granule layout unchanged: G(R,kc) at
// (R>>3)*1024 + (R&7)*128 + ((kc^(R&7))*16.
template <int OUTBF16>
__global__ __launch_bounds__(512, 2) void gemm8p(const short* __restrict__ A,
    const short* __restrict__ B, void* __restrict__ C, int M, int N, int Kd) {
  __shared__ short lds[65536];  // 128 KiB: buf{0,1} x [A 32K | B 32K]
  const int tid = threadIdx.x;
  const int lane = tid & 63;
  const int wid = tid >> 6;        // 0..7
  const int wr = wid >> 2;         // 0..1  (M half)
  const int wcn = wid & 3;         // 0..3  (N quarter)
  const int l7 = lane & 7;
  const int l31g = (lane & 31) >> 3;   // row-group within 32-row frag
  const int hi = lane >> 5;            // k-granule half

  const int nbx = N >> 8;
  const int cpx = gridDim.x >> 3;
  const int wg = ((int)blockIdx.x & 7) * cpx + ((int)blockIdx.x >> 3);
  const long m0 = (long)(wg / nbx) * 256;
  const long n0 = (long)(wg % nbx) * 256;

  const int NT = Kd >> 6;

  const int rho = lane >> 3;
  const short* Ag = A + (m0 + wid * 8 + rho) * (long)Kd + (l7 ^ rho) * 8;
  const short* Bg = B + (n0 + wid * 8 + rho) * (long)Kd + (l7 ^ rho) * 8;

#define STAGE_A(b, kt, c) GLOAD16(Ag + (long)(c) * 64 * Kd + (long)(kt) * 64, \
    (char*)lds + (b) * 65536 + ((c) * 8 + wid) * 1024 + lane * 16)
#define STAGE_B(b, kt, c) GLOAD16(Bg + (long)(c) * 64 * Kd + (long)(kt) * 64, \
    (char*)lds + (b) * 65536 + 32768 + ((c) * 8 + wid) * 1024 + lane * 16)

  // 32x32 fragment read offsets: A chunk q adds q*8192; s = k-step (K=16 each)
  int aOff[4], bOff[2][4];
  #pragma unroll
  for (int s = 0; s < 4; ++s) {
    aOff[s] = (wr * 4 + l31g) * 1024 + l7 * 128 + (((s * 2 + hi) ^ l7)) * 16;
    #pragma unroll
    for (int nf = 0; nf < 2; ++nf)
      bOff[nf][s] = 32768 + (wcn * 8 + nf * 4 + l31g) * 1024 + l7 * 128 +
                    (((s * 2 + hi) ^ l7)) * 16;
  }

#define READ_A(dst, buf, c)                                                   \
  do {                                                                        \
    _Pragma("unroll")                                                         \
    for (int s = 0; s < 4; ++s)                                               \
      dst[s] = *(const bf16x8*)((buf) + (c) * 8192 + aOff[s]);                \
  } while (0)

#define READ_B(buf)                                                           \
  do {                                                                        \
    _Pragma("unroll")                                                         \
    for (int nf = 0; nf < 2; ++nf)                                            \
      _Pragma("unroll")                                                       \
      for (int s = 0; s < 4; ++s)                                             \
        bv[nf][s] = *(const bf16x8*)((buf) + bOff[nf][s]);                    \
  } while (0)

#define MFMA_BLOCK(q, av)                                                     \
  do {                                                                        \
    _Pragma("unroll")                                                         \
    for (int s = 0; s < 4; ++s)                                               \
      _Pragma("unroll")                                                       \
      for (int nf = 0; nf < 2; ++nf)                                          \
        acc[q][nf] = __builtin_amdgcn_mfma_f32_32x32x16_bf16(                 \
            av[s], bv[nf][s], acc[q][nf], 0, 0, 0);                           \
  } while (0)

  f32x16 acc[4][2];
  #pragma unroll
  for (int m = 0; m < 4; ++m)
    #pragma unroll
    for (int n = 0; n < 2; ++n)
      #pragma unroll
      for (int j = 0; j < 16; ++j) acc[m][n][j] = 0.f;

  // -------- prologue: tile0 (8 chunk-pairs) + tile1 chunks 0..2 --------
  STAGE_A(0, 0, 0); STAGE_B(0, 0, 0);
  STAGE_A(0, 0, 1); STAGE_B(0, 0, 1);
  STAGE_A(0, 0, 2); STAGE_B(0, 0, 2);
  STAGE_A(0, 0, 3); STAGE_B(0, 0, 3);
  STAGE_A(1, 1, 0); STAGE_B(1, 1, 0);
  STAGE_A(1, 1, 1); STAGE_B(1, 1, 1);
  STAGE_A(1, 1, 2); STAGE_B(1, 1, 2);
  asm volatile("s_waitcnt vmcnt(6)" ::: "memory");
  __builtin_amdgcn_s_barrier();
  asm volatile("" ::: "memory");

  const char* ldsb = (const char*)lds;
  bf16x8 avX[4], avY[4], bv[2][4];
  READ_B(ldsb);
  READ_A(avX, ldsb, 0);

  for (int t = 0; t < NT; ++t) {
    const int cur = t & 1;
    const int tn1 = (t + 1 < NT) ? t + 1 : 0;   // wrap -> garbage stage, safe
    const int tn2 = (t + 2 < NT) ? t + 2 : 0;
    const char* pc = ldsb + cur * 65536;
    const char* pn = ldsb + (cur ^ 1) * 65536;

    // ---- phase 0: prefetch ch1 -> avY; MFMA ch0 (avX) ----
    READ_A(avY, pc, 1);
    STAGE_A(cur ^ 1, tn1, 3); STAGE_B(cur ^ 1, tn1, 3);
    __builtin_amdgcn_s_barrier();
    asm volatile("s_waitcnt lgkmcnt(4)" ::: "memory");
    __builtin_amdgcn_sched_barrier(0);
    __builtin_amdgcn_s_setprio(1);
    MFMA_BLOCK(0, avX);
    __builtin_amdgcn_s_setprio(0);
    __builtin_amdgcn_s_barrier();
    asm volatile("" ::: "memory");

    // ---- phase 1: prefetch ch2 -> avX; MFMA ch1 (avY) ----
    READ_A(avX, pc, 2);
    STAGE_A(cur, tn2, 0); STAGE_B(cur, tn2, 0);
    __builtin_amdgcn_s_barrier();
    asm volatile("s_waitcnt lgkmcnt(4)" ::: "memory");
    __builtin_amdgcn_sched_barrier(0);
    __builtin_amdgcn_s_setprio(1);
    MFMA_BLOCK(1, avY);
    __builtin_amdgcn_s_setprio(0);
    __builtin_amdgcn_s_barrier();
    asm volatile("" ::: "memory");

    // ---- phase 2: prefetch ch3 -> avY; MFMA ch2 (avX) ----
    READ_A(avY, pc, 3);
    STAGE_A(cur, tn2, 1); STAGE_B(cur, tn2, 1);
    __builtin_amdgcn_s_barrier();
    asm volatile("s_waitcnt lgkmcnt(4)" ::: "memory");
    __builtin_amdgcn_sched_barrier(0);
    __builtin_amdgcn_s_setprio(1);
    MFMA_BLOCK(2, avX);
    __builtin_amdgcn_s_setprio(0);
    __builtin_amdgcn_s_barrier();
    asm volatile("" ::: "memory");

    // ---- phase 3: MFMA ch3 (avY); then prefetch next tile B + ch0 -> avX ----
    STAGE_A(cur, tn2, 2); STAGE_B(cur, tn2, 2);
    asm volatile("s_waitcnt vmcnt(6)" ::: "memory");
    __builtin_amdgcn_s_barrier();
    asm volatile("s_waitcnt lgkmcnt(0)" ::: "memory");
    __builtin_amdgcn_sched_barrier(0);
    __builtin_amdgcn_s_setprio(1);
    MFMA_BLOCK(3, avY);
    __builtin_amdgcn_s_setprio(0);
    __builtin_amdgcn_sched_barrier(0);
    READ_B(pn);
    READ_A(avX, pn, 0);
    __builtin_amdgcn_s_barrier();
    asm volatile("" ::: "memory");
  }
#undef STAGE_A
#undef STAGE_B
#undef READ_A
#undef READ_B
#undef MFMA_BLOCK

  // -------- epilogue: C write (32x32 C layout) --------
  #pragma unroll
  for (int q = 0; q < 4; ++q)
    #pragma unroll
    for (int nf = 0; nf < 2; ++nf)
      #pragma unroll
      for (int reg = 0; reg < 16; ++reg) {
        const long row = m0 + q * 64 + wr * 32 + (reg & 3) + 8 * (reg >> 2) + 4 * hi;
        const long col = n0 + wcn * 64 + nf * 32 + (lane & 31);
        if (OUTBF16) ((short*)C)[row * N + col] = f2b(acc[q][nf][reg]);
        else         ((float*)C)[row * N + col] = acc[q][nf][reg];
      }
}

// ---------------- skinny GEMM: out[t][16] = X[t,:] @ W[16,K]^T ----------------
__global__ __launch_bounds__(256) void rowgemm16(const short* __restrict__ X,
    const short* __restrict__ W, float* __restrict__ out, int K, long wStride) {
  const int lane = threadIdx.x & 63;
  const int token = blockIdx.x * 4 + (threadIdx.x >> 6);
  const short* Xr = X + (long)token * K;
  const short* Wr = W + (long)(token >> 6) * wStride;
  float acc[16];
  #pragma unroll
  for (int r = 0; r < 16; ++r) acc[r] = 0.f;
  const int nIter = (K + 511) >> 9;
  for (int i = 0; i < nIter; ++i) {
    const int k = i * 512 + lane * 8;
    if (k + 8 <= K) {
      bf16x8 xv = *(const bf16x8*)(Xr + k);
      float xf[8];
      #pragma unroll
      for (int j = 0; j < 8; ++j) xf[j] = b2f(xv[j]);
      #pragma unroll
      for (int r = 0; r < 16; ++r) {
        bf16x8 wv = *(const bf16x8*)(Wr + (long)r * K + k);
        #pragma unroll
        for (int j = 0; j < 8; ++j) acc[r] = fmaf(xf[j], b2f(wv[j]), acc[r]);
      }
    }
  }
  #pragma unroll
  for (int r = 0; r < 16; ++r) {
    float v = acc[r];
    #pragma unroll
    for (int off = 32; off > 0; off >>= 1) v += __shfl_xor(v, off, 64);
    acc[r] = v;
  }
  if (lane == 0) {
    #pragma unroll
    for (int r = 0; r < 16; ++r) out[(long)token * 16 + r] = acc[r];
  }
}

// ---------------- pass 1a: dA[chunk][h][r] = sum_c V[c,h]*pin[c,r] ----------------
__global__ __launch_bounds__(256) void dA_kernel(const short* __restrict__ V,
    const float* __restrict__ pin, float* __restrict__ dA) {
  const int chunk = blockIdx.y;
  const int h = blockIdx.x * 256 + threadIdx.x;
  __shared__ float ps[1024];
  #pragma unroll
  for (int i = 0; i < 4; ++i)
    ps[i * 256 + threadIdx.x] = pin[(long)chunk * 1024 + i * 256 + threadIdx.x];
  __syncthreads();
  float acc[16];
  #pragma unroll
  for (int r = 0; r < 16; ++r) acc[r] = 0.f;
  for (int c = 0; c < 64; ++c) {
    const float v = b2f(V[((long)chunk * 64 + c) * 4096 + h]);
    #pragma unroll
    for (int r = 0; r < 16; ++r) acc[r] = fmaf(v, ps[c * 16 + r], acc[r]);
  }
  float* dst = dA + ((long)chunk * 4096 + h) * 16;
  #pragma unroll
  for (int i = 0; i < 4; ++i) {
    f32x4 w; w[0] = acc[i*4]; w[1] = acc[i*4+1]; w[2] = acc[i*4+2]; w[3] = acc[i*4+3];
    *(f32x4*)(dst + i * 4) = w;
  }
}

// ---------------- pass 1b: dB[chunk][r][k] = sum_c per[c,r]*X[c,k] ----------------
__global__ __launch_bounds__(256) void dB_kernel(const short* __restrict__ X,
    const float* __restrict__ per, float* __restrict__ dB) {
  const int chunk = blockIdx.y;
  const int k = blockIdx.x * 256 + threadIdx.x;   // 43*256 == 11008
  __shared__ float ps[1024];
  #pragma unroll
  for (int i = 0; i < 4; ++i)
    ps[i * 256 + threadIdx.x] = per[(long)chunk * 1024 + i * 256 + threadIdx.x];
  __syncthreads();
  float acc[16];
  #pragma unroll
  for (int r = 0; r < 16; ++r) acc[r] = 0.f;
  for (int c = 0; c < 64; ++c) {
    const float xv = b2f(X[((long)chunk * 64 + c) * 11008 + k]);
    #pragma unroll
    for (int r = 0; r < 16; ++r) acc[r] = fmaf(xv, ps[c * 16 + r], acc[r]);
  }
  #pragma unroll
  for (int r = 0; r < 16; ++r)
    dB[((long)chunk * 16 + r) * 11008 + k] = acc[r];
}

// ---------- pass 2a: exclusive scan over chunks -> A_eff bf16 ----------
__global__ __launch_bounds__(256) void scanA_kernel(const float* __restrict__ dA,
    const float* __restrict__ initA, short* __restrict__ Aeff) {
  const int b = blockIdx.y;
  const long idx = (long)blockIdx.x * 256 + threadIdx.x;  // h*16+r, < 65536
  const float a0 = initA[idx];
  float acc = 0.f;
  for (int n = 0; n < 32; ++n) {
    const long chunk = (long)b * 32 + n;
    Aeff[chunk * 65536 + idx] = f2b(a0 - 0.02f * acc);
    acc += dA[chunk * 65536 + idx];
  }
}

// ---------- pass 2b: exclusive scan over chunks -> B_eff bf16 ----------
__global__ __launch_bounds__(256) void scanB_kernel(const float* __restrict__ dB,
    const float* __restrict__ initB, short* __restrict__ Beff) {
  const int b = blockIdx.y;
  const long idx = (long)blockIdx.x * 256 + threadIdx.x;  // r*11008+k, < 176128
  const float b0 = initB[idx];
  float acc = 0.f;
  for (int n = 0; n < 32; ++n) {
    const long chunk = (long)b * 32 + n;
    Beff[chunk * 176128 + idx] = f2b(b0 - 0.02f * acc);
    acc += dB[chunk * 176128 + idx];
  }
}

// ---------------- out(f32) = base(bf16) + 2 * mid @ A_eff^T ----------------
__global__ __launch_bounds__(256) void final_kernel(const short* __restrict__ base,
    const float* __restrict__ mid, const short* __restrict__ Aeff,
    float* __restrict__ out) {
  const int token = blockIdx.x;
  const int chunk = token >> 6;
  __shared__ float m[16];
  if (threadIdx.x < 16) m[threadIdx.x] = mid[(long)token * 16 + threadIdx.x];
  __syncthreads();
  float mf[16];
  #pragma unroll
  for (int r = 0; r < 16; ++r) mf[r] = m[r];
  for (int it = 0; it < 2; ++it) {
    const int h0 = it * 2048 + threadIdx.x * 8;
    bf16x8 bs = *(const bf16x8*)(base + (long)token * 4096 + h0);
    float res[8];
    #pragma unroll
    for (int j = 0; j < 8; ++j) {
      const short* ar = Aeff + ((long)chunk * 4096 + h0 + j) * 16;
      bf16x8 a0 = *(const bf16x8*)ar;
      bf16x8 a1 = *(const bf16x8*)(ar + 8);
      float s = 0.f;
      #pragma unroll
      for (int r = 0; r < 8; ++r) {
        s = fmaf(mf[r], b2f(a0[r]), s);
        s = fmaf(mf[r + 8], b2f(a1[r]), s);
      }
      res[j] = b2f(bs[j]) + 2.0f * s;
    }
    #pragma unroll
    for (int i = 0; i < 2; ++i) {
      f32x4 w; w[0] = res[i*4]; w[1] = res[i*4+1]; w[2] = res[i*4+2]; w[3] = res[i*4+3];
      *(f32x4*)(out + (long)token * 4096 + h0 + i * 4) = w;
    }
  }
}

extern "C" void kernel_launch(void* const* d_in, const int* in_sizes, int n_in,
                              void* d_out, int out_size, void* d_ws, size_t ws_size,
                              hipStream_t stream) {
  const float* x     = (const float*)d_in[0];   // [2,2048,11008]
  const float* Wbase = (const float*)d_in[1];   // [4096,11008]
  const float* emb   = (const float*)d_in[2];   // [32000,4096]
  const float* Wproj = (const float*)d_in[3];   // [4096,4096]
  const float* initA = (const float*)d_in[4];   // [4096,16]
  const float* initB = (const float*)d_in[5];   // [16,11008]
  const int*   ids   = (const int*)d_in[6];     // [2,2048]
  float* outp = (float*)d_out;                  // f32 [2,2048,4096]

  char* p = (char*)d_ws;
  short* xb   = (short*)p; p += 90177536L;   // x bf16
  short* Wb   = (short*)p; p += 90177536L;   // W_base bf16
  short* Wpb  = (short*)p; p += 33554432L;   // W_proj bf16 (dead after V GEMM)
  short* shb  = (short*)p; p += 33554432L;   // shifted embeds bf16 (dead after V GEMM)
  short* Vb   = (short*)p; p += 33554432L;   // V bf16
  short* base = (short*)p; p += 33554432L;   // base_out bf16
  short* iBb  = (short*)p; p += 352256L;     // init_B bf16
  short* iAt  = (short*)p; p += 131072L;     // init_A^T bf16 [16][4096]
  float* pin  = (float*)p; p += 262144L;     // proj_in f32 [4096][16]
  float* per  = (float*)p; p += 262144L;     // proj_err f32 [4096][16]
  float* mid  = (float*)p; p += 262144L;     // mid f32 [4096][16]
  short* Aeff = (short*)p; p += 8388608L;    // [64][4096][16] bf16
  short* Beff = (short*)p; p += 22544384L;   // [64][16][11008] bf16
  // dA/dB alias Wpb+shb (live only after V GEMM): 16MB + 45MB < 64MB
  float* dA = (float*)Wpb;
  float* dB = (float*)((char*)Wpb + 16777216L);

  cvt_kernel<<<2048, 256, 0, stream>>>(x, xb, 45088768L);
  cvt_kernel<<<2048, 256, 0, stream>>>(Wbase, Wb, 45088768L);
  cvt_kernel<<<2048, 256, 0, stream>>>(Wproj, Wpb, 16777216L);
  cvt_kernel<<<86, 256, 0, stream>>>(initB, iBb, 176128L);
  tposeA_kernel<<<16, 256, 0, stream>>>(initA, iAt);
  gather_kernel<<<4096, 256, 0, stream>>>(emb, ids, shb);

  gemm8p<1><<<256, 512, 0, stream>>>(shb, Wpb, (void*)Vb, 4096, 4096, 4096);
  gemm8p<1><<<256, 512, 0, stream>>>(xb, Wb, (void*)base, 4096, 4096, 11008);

  rowgemm16<<<1024, 256, 0, stream>>>(xb, iBb, pin, 11008, 0L);   // proj_in
  rowgemm16<<<1024, 256, 0, stream>>>(Vb, iAt, per, 4096, 0L);    // proj_err

  dA_kernel<<<dim3(16, 64), 256, 0, stream>>>(Vb, pin, dA);
  dB_kernel<<<dim3(43, 64), 256, 0, stream>>>(xb, per, dB);
  scanA_kernel<<<dim3(256, 2), 256, 0, stream>>>(dA, initA, Aeff);
  scanB_kernel<<<dim3(688, 2), 256, 0, stream>>>(dB, initB, Beff);

  rowgemm16<<<1024, 256, 0, stream>>>(xb, Beff, mid, 11008, 176128L);  // mid
  final_kernel<<<4096, 256, 0, stream>>>(base, mid, Aeff, outp);
}

// Round 8
// 898.234 us; speedup vs baseline: 1.0497x; 1.0497x over previous
//
#include <hip/hip_runtime.h>

typedef __attribute__((ext_vector_type(8))) short bf16x8;
typedef __attribute__((ext_vector_type(4))) float f32x4;

__device__ __forceinline__ float b2f(short s) {
  return __uint_as_float(((unsigned int)(unsigned short)s) << 16);
}
__device__ __forceinline__ short f2b(float f) {
  unsigned int u = __float_as_uint(f);
  unsigned int r = (u + 0x7fffu + ((u >> 16) & 1u)) >> 16;
  return (short)(unsigned short)r;
}

#define GLOAD16(g, l) __builtin_amdgcn_global_load_lds( \
    (const __attribute__((address_space(1))) void*)(g),  \
    (__attribute__((address_space(3))) void*)(l), 16, 0, 0)

// ---------------- f32 -> bf16 convert ----------------
__global__ __launch_bounds__(256) void cvt_kernel(const float* __restrict__ src,
                                                  short* __restrict__ dst, long n) {
  long i = ((long)blockIdx.x * 256 + threadIdx.x) * 8;
  long stride = (long)gridDim.x * 256 * 8;
  for (; i + 8 <= n; i += stride) {
    float4 a = *(const float4*)(src + i);
    float4 b = *(const float4*)(src + i + 4);
    bf16x8 o;
    o[0] = f2b(a.x); o[1] = f2b(a.y); o[2] = f2b(a.z); o[3] = f2b(a.w);
    o[4] = f2b(b.x); o[5] = f2b(b.y); o[6] = f2b(b.z); o[7] = f2b(b.w);
    *(bf16x8*)(dst + i) = o;
  }
}

// ---------------- gather next-token embeddings, shift, convert ----------------
__global__ __launch_bounds__(256) void gather_kernel(const float* __restrict__ emb,
    const int* __restrict__ ids, short* __restrict__ sh) {
  const int token = blockIdx.x;          // 0..4095, token = b*2048 + s
  const int s = token & 2047;
  const long dst = (long)token * 4096;
  const int row = (s == 2047) ? -1 : ids[token + 1];
  for (int it = 0; it < 2; ++it) {
    const int e = it * 2048 + threadIdx.x * 8;
    bf16x8 o;
    if (row < 0) {
      #pragma unroll
      for (int j = 0; j < 8; ++j) o[j] = 0;
    } else {
      float4 a = *(const float4*)(emb + (long)row * 4096 + e);
      float4 b = *(const float4*)(emb + (long)row * 4096 + e + 4);
      o[0] = f2b(a.x); o[1] = f2b(a.y); o[2] = f2b(a.z); o[3] = f2b(a.w);
      o[4] = f2b(b.x); o[5] = f2b(b.y); o[6] = f2b(b.z); o[7] = f2b(b.w);
    }
    *(bf16x8*)(sh + dst + e) = o;
  }
}

// ---------------- init_A [4096][16] f32 -> [16][4096] bf16 ----------------
__global__ __launch_bounds__(256) void tposeA_kernel(const float* __restrict__ A,
                                                     short* __restrict__ At) {
  const int h = blockIdx.x * 256 + threadIdx.x;
  #pragma unroll
  for (int r = 0; r < 16; ++r) At[(long)r * 4096 + h] = f2b(A[(long)h * 16 + r]);
}

// ======== deep-pipelined 256x256 MFMA GEMM: C[M,N] = A[M,K] @ B[N,K]^T ========
// Round-8: back to the verified 16x16x32 r6 kernel, with phases merged 4 -> 2
// per K-tile (4 barriers instead of 8, 2 lgkm waits instead of 4, same single
// vmcnt(6)). Stage issue order per tile unchanged: (t+1,c3),(t+2,c0),(t+2,c1),
// (t+2,c2); LDS WAR invariant kept: each chunk's overwrite is issued only
// after the lgkm wait that drained its readers (c0 staged post-MFMA in phA).
template <int OUTBF16>
__global__ __launch_bounds__(512, 2) void gemm8p(const short* __restrict__ A,
    const short* __restrict__ B, void* __restrict__ C, int M, int N, int Kd) {
  __shared__ short lds[65536];  // 128 KiB: buf{0,1} x [A 32K | B 32K]
  const int tid = threadIdx.x;
  const int lane = tid & 63;
  const int wid = tid >> 6;        // 0..7
  const int wr = wid >> 2;         // 0..1  (M half)
  const int wcn = wid & 3;         // 0..3  (N quarter)
  const int l15 = lane & 15, l4 = lane >> 4, l7 = lane & 7;
  const int lb = (lane >> 3) & 1;

  const int nbx = N >> 8;
  const int cpx = gridDim.x >> 3;
  const int wg = ((int)blockIdx.x & 7) * cpx + ((int)blockIdx.x >> 3);
  const long m0 = (long)(wg / nbx) * 256;
  const long n0 = (long)(wg % nbx) * 256;

  const int NT = Kd >> 6;

  const int rho = lane >> 3;
  const short* Ag = A + (m0 + wid * 8 + rho) * (long)Kd + (l7 ^ rho) * 8;
  const short* Bg = B + (n0 + wid * 8 + rho) * (long)Kd + (l7 ^ rho) * 8;

#define STAGE_A(b, kt, c) GLOAD16(Ag + (long)(c) * 64 * Kd + (long)(kt) * 64, \
    (char*)lds + (b) * 65536 + ((c) * 8 + wid) * 1024 + lane * 16)
#define STAGE_B(b, kt, c) GLOAD16(Bg + (long)(c) * 64 * Kd + (long)(kt) * 64, \
    (char*)lds + (b) * 65536 + 32768 + ((c) * 8 + wid) * 1024 + lane * 16)

  int aLane[2];
  #pragma unroll
  for (int h = 0; h < 2; ++h)
    aLane[h] = (lb * 64 + l7 * 8 + ((h * 4 + l4) ^ l7)) * 16;

#define READ_A1(dst, buf, c)                                                  \
  do {                                                                        \
    _Pragma("unroll")                                                         \
    for (int sub = 0; sub < 2; ++sub) {                                       \
      dst[sub][0] = *(const bf16x8*)((buf) + (c) * 8192 + wr * 4096 +         \
                                     sub * 2048 + aLane[0]);                  \
      dst[sub][1] = *(const bf16x8*)((buf) + (c) * 8192 + wr * 4096 +         \
                                     sub * 2048 + aLane[1]);                  \
    }                                                                         \
  } while (0)

#define READ_B(buf)                                                           \
  do {                                                                        \
    _Pragma("unroll")                                                         \
    for (int nf = 0; nf < 4; ++nf) {                                          \
      bv[nf][0] = *(const bf16x8*)((buf) + 32768 + wcn * 8192 + nf * 2048 +   \
                                   aLane[0]);                                 \
      bv[nf][1] = *(const bf16x8*)((buf) + 32768 + wcn * 8192 + nf * 2048 +   \
                                   aLane[1]);                                 \
    }                                                                         \
  } while (0)

#define MFMA_CH(q, av)                                                        \
  do {                                                                        \
    _Pragma("unroll")                                                         \
    for (int sub = 0; sub < 2; ++sub)                                         \
      _Pragma("unroll")                                                       \
      for (int nf = 0; nf < 4; ++nf) {                                        \
        acc[(q) * 2 + sub][nf] = __builtin_amdgcn_mfma_f32_16x16x32_bf16(     \
            av[sub][0], bv[nf][0], acc[(q) * 2 + sub][nf], 0, 0, 0);          \
        acc[(q) * 2 + sub][nf] = __builtin_amdgcn_mfma_f32_16x16x32_bf16(     \
            av[sub][1], bv[nf][1], acc[(q) * 2 + sub][nf], 0, 0, 0);          \
      }                                                                       \
  } while (0)

  f32x4 acc[8][4];
  #pragma unroll
  for (int m = 0; m < 8; ++m)
    #pragma unroll
    for (int n = 0; n < 4; ++n) {
      acc[m][n][0] = 0.f; acc[m][n][1] = 0.f;
      acc[m][n][2] = 0.f; acc[m][n][3] = 0.f;
    }

  // -------- prologue: tile0 (8 chunk-pairs) + tile1 chunks 0..2 --------
  STAGE_A(0, 0, 0); STAGE_B(0, 0, 0);
  STAGE_A(0, 0, 1); STAGE_B(0, 0, 1);
  STAGE_A(0, 0, 2); STAGE_B(0, 0, 2);
  STAGE_A(0, 0, 3); STAGE_B(0, 0, 3);
  STAGE_A(1, 1, 0); STAGE_B(1, 1, 0);
  STAGE_A(1, 1, 1); STAGE_B(1, 1, 1);
  STAGE_A(1, 1, 2); STAGE_B(1, 1, 2);
  asm volatile("s_waitcnt vmcnt(6)" ::: "memory");
  __builtin_amdgcn_s_barrier();
  asm volatile("" ::: "memory");

  const char* ldsb = (const char*)lds;
  bf16x8 avX[2][2][2], avY[2][2][2], bv[4][2];
  READ_B(ldsb);
  READ_A1(avX[0], ldsb, 0);
  READ_A1(avX[1], ldsb, 1);

  for (int t = 0; t < NT; ++t) {
    const int cur = t & 1;
    const int tn1 = (t + 1 < NT) ? t + 1 : 0;   // wrap -> garbage stage, safe
    const int tn2 = (t + 2 < NT) ? t + 2 : 0;
    const char* pc = ldsb + cur * 65536;
    const char* pn = ldsb + (cur ^ 1) * 65536;

    // ---- phase A: prefetch ch2,ch3 -> avY; MFMA ch0,ch1 (avX) ----
    READ_A1(avY[0], pc, 2);
    READ_A1(avY[1], pc, 3);
    STAGE_A(cur ^ 1, tn1, 3); STAGE_B(cur ^ 1, tn1, 3);
    __builtin_amdgcn_s_barrier();
    asm volatile("s_waitcnt lgkmcnt(8)" ::: "memory");
    __builtin_amdgcn_sched_barrier(0);
    __builtin_amdgcn_s_setprio(1);
    MFMA_CH(0, avX[0]);
    MFMA_CH(1, avX[1]);
    __builtin_amdgcn_s_setprio(0);
    __builtin_amdgcn_sched_barrier(0);
    STAGE_A(cur, tn2, 0); STAGE_B(cur, tn2, 0);   // ch0 readers drained above
    __builtin_amdgcn_s_barrier();
    asm volatile("" ::: "memory");

    // ---- phase B: MFMA ch2,ch3 (avY); prefetch next tile ch0,ch1 + B ----
    STAGE_A(cur, tn2, 1); STAGE_B(cur, tn2, 1);
    STAGE_A(cur, tn2, 2); STAGE_B(cur, tn2, 2);
    asm volatile("s_waitcnt vmcnt(6)" ::: "memory");
    __builtin_amdgcn_s_barrier();
    READ_A1(avX[0], pn, 0);
    READ_A1(avX[1], pn, 1);
    asm volatile("s_waitcnt lgkmcnt(8)" ::: "memory");
    __builtin_amdgcn_sched_barrier(0);
    __builtin_amdgcn_s_setprio(1);
    MFMA_CH(2, avY[0]);
    MFMA_CH(3, avY[1]);
    __builtin_amdgcn_s_setprio(0);
    __builtin_amdgcn_sched_barrier(0);
    READ_B(pn);
    __builtin_amdgcn_s_barrier();
    asm volatile("" ::: "memory");
  }
#undef STAGE_A
#undef STAGE_B
#undef READ_A1
#undef READ_B
#undef MFMA_CH

  // -------- epilogue: C write --------
  #pragma unroll
  for (int q = 0; q < 4; ++q)
    #pragma unroll
    for (int sub = 0; sub < 2; ++sub)
      #pragma unroll
      for (int nf = 0; nf < 4; ++nf)
        #pragma unroll
        for (int j = 0; j < 4; ++j) {
          const long row = m0 + q * 64 + wr * 32 + sub * 16 + l4 * 4 + j;
          const long col = n0 + wcn * 64 + nf * 16 + l15;
          if (OUTBF16) ((short*)C)[row * N + col] = f2b(acc[q * 2 + sub][nf][j]);
          else         ((float*)C)[row * N + col] = acc[q * 2 + sub][nf][j];
        }
}

// ---------------- skinny GEMM: out[t][16] = X[t,:] @ W[16,K]^T ----------------
__global__ __launch_bounds__(256) void rowgemm16(const short* __restrict__ X,
    const short* __restrict__ W, float* __restrict__ out, int K, long wStride) {
  const int lane = threadIdx.x & 63;
  const int token = blockIdx.x * 4 + (threadIdx.x >> 6);
  const short* Xr = X + (long)token * K;
  const short* Wr = W + (long)(token >> 6) * wStride;
  float acc[16];
  #pragma unroll
  for (int r = 0; r < 16; ++r) acc[r] = 0.f;
  const int nIter = (K + 511) >> 9;
  for (int i = 0; i < nIter; ++i) {
    const int k = i * 512 + lane * 8;
    if (k + 8 <= K) {
      bf16x8 xv = *(const bf16x8*)(Xr + k);
      float xf[8];
      #pragma unroll
      for (int j = 0; j < 8; ++j) xf[j] = b2f(xv[j]);
      #pragma unroll
      for (int r = 0; r < 16; ++r) {
        bf16x8 wv = *(const bf16x8*)(Wr + (long)r * K + k);
        #pragma unroll
        for (int j = 0; j < 8; ++j) acc[r] = fmaf(xf[j], b2f(wv[j]), acc[r]);
      }
    }
  }
  #pragma unroll
  for (int r = 0; r < 16; ++r) {
    float v = acc[r];
    #pragma unroll
    for (int off = 32; off > 0; off >>= 1) v += __shfl_xor(v, off, 64);
    acc[r] = v;
  }
  if (lane == 0) {
    #pragma unroll
    for (int r = 0; r < 16; ++r) out[(long)token * 16 + r] = acc[r];
  }
}

// ---------------- pass 1a: dA[chunk][h][r] = sum_c V[c,h]*pin[c,r] ----------------
__global__ __launch_bounds__(256) void dA_kernel(const short* __restrict__ V,
    const float* __restrict__ pin, float* __restrict__ dA) {
  const int chunk = blockIdx.y;
  const int h = blockIdx.x * 256 + threadIdx.x;
  __shared__ float ps[1024];
  #pragma unroll
  for (int i = 0; i < 4; ++i)
    ps[i * 256 + threadIdx.x] = pin[(long)chunk * 1024 + i * 256 + threadIdx.x];
  __syncthreads();
  float acc[16];
  #pragma unroll
  for (int r = 0; r < 16; ++r) acc[r] = 0.f;
  for (int c = 0; c < 64; ++c) {
    const float v = b2f(V[((long)chunk * 64 + c) * 4096 + h]);
    #pragma unroll
    for (int r = 0; r < 16; ++r) acc[r] = fmaf(v, ps[c * 16 + r], acc[r]);
  }
  float* dst = dA + ((long)chunk * 4096 + h) * 16;
  #pragma unroll
  for (int i = 0; i < 4; ++i) {
    f32x4 w; w[0] = acc[i*4]; w[1] = acc[i*4+1]; w[2] = acc[i*4+2]; w[3] = acc[i*4+3];
    *(f32x4*)(dst + i * 4) = w;
  }
}

// ---------------- pass 1b: dB[chunk][r][k] = sum_c per[c,r]*X[c,k] ----------------
__global__ __launch_bounds__(256) void dB_kernel(const short* __restrict__ X,
    const float* __restrict__ per, float* __restrict__ dB) {
  const int chunk = blockIdx.y;
  const int k = blockIdx.x * 256 + threadIdx.x;   // 43*256 == 11008
  __shared__ float ps[1024];
  #pragma unroll
  for (int i = 0; i < 4; ++i)
    ps[i * 256 + threadIdx.x] = per[(long)chunk * 1024 + i * 256 + threadIdx.x];
  __syncthreads();
  float acc[16];
  #pragma unroll
  for (int r = 0; r < 16; ++r) acc[r] = 0.f;
  for (int c = 0; c < 64; ++c) {
    const float xv = b2f(X[((long)chunk * 64 + c) * 11008 + k]);
    #pragma unroll
    for (int r = 0; r < 16; ++r) acc[r] = fmaf(xv, ps[c * 16 + r], acc[r]);
  }
  #pragma unroll
  for (int r = 0; r < 16; ++r)
    dB[((long)chunk * 16 + r) * 11008 + k] = acc[r];
}

// ---------- pass 2a: exclusive scan over chunks -> A_eff bf16 ----------
__global__ __launch_bounds__(256) void scanA_kernel(const float* __restrict__ dA,
    const float* __restrict__ initA, short* __restrict__ Aeff) {
  const int b = blockIdx.y;
  const long idx = (long)blockIdx.x * 256 + threadIdx.x;  // h*16+r, < 65536
  const float a0 = initA[idx];
  float acc = 0.f;
  for (int n = 0; n < 32; ++n) {
    const long chunk = (long)b * 32 + n;
    Aeff[chunk * 65536 + idx] = f2b(a0 - 0.02f * acc);
    acc += dA[chunk * 65536 + idx];
  }
}

// ---------- pass 2b: exclusive scan over chunks -> B_eff bf16 ----------
__global__ __launch_bounds__(256) void scanB_kernel(const float* __restrict__ dB,
    const float* __restrict__ initB, short* __restrict__ Beff) {
  const int b = blockIdx.y;
  const long idx = (long)blockIdx.x * 256 + threadIdx.x;  // r*11008+k, < 176128
  const float b0 = initB[idx];
  float acc = 0.f;
  for (int n = 0; n < 32; ++n) {
    const long chunk = (long)b * 32 + n;
    Beff[chunk * 176128 + idx] = f2b(b0 - 0.02f * acc);
    acc += dB[chunk * 176128 + idx];
  }
}

// ---------------- out(f32) = base(bf16) + 2 * mid @ A_eff^T ----------------
__global__ __launch_bounds__(256) void final_kernel(const short* __restrict__ base,
    const float* __restrict__ mid, const short* __restrict__ Aeff,
    float* __restrict__ out) {
  const int token = blockIdx.x;
  const int chunk = token >> 6;
  __shared__ float m[16];
  if (threadIdx.x < 16) m[threadIdx.x] = mid[(long)token * 16 + threadIdx.x];
  __syncthreads();
  float mf[16];
  #pragma unroll
  for (int r = 0; r < 16; ++r) mf[r] = m[r];
  for (int it = 0; it < 2; ++it) {
    const int h0 = it * 2048 + threadIdx.x * 8;
    bf16x8 bs = *(const bf16x8*)(base + (long)token * 4096 + h0);
    float res[8];
    #pragma unroll
    for (int j = 0; j < 8; ++j) {
      const short* ar = Aeff + ((long)chunk * 4096 + h0 + j) * 16;
      bf16x8 a0 = *(const bf16x8*)ar;
      bf16x8 a1 = *(const bf16x8*)(ar + 8);
      float s = 0.f;
      #pragma unroll
      for (int r = 0; r < 8; ++r) {
        s = fmaf(mf[r], b2f(a0[r]), s);
        s = fmaf(mf[r + 8], b2f(a1[r]), s);
      }
      res[j] = b2f(bs[j]) + 2.0f * s;
    }
    #pragma unroll
    for (int i = 0; i < 2; ++i) {
      f32x4 w; w[0] = res[i*4]; w[1] = res[i*4+1]; w[2] = res[i*4+2]; w[3] = res[i*4+3];
      *(f32x4*)(out + (long)token * 4096 + h0 + i * 4) = w;
    }
  }
}

extern "C" void kernel_launch(void* const* d_in, const int* in_sizes, int n_in,
                              void* d_out, int out_size, void* d_ws, size_t ws_size,
                              hipStream_t stream) {
  const float* x     = (const float*)d_in[0];   // [2,2048,11008]
  const float* Wbase = (const float*)d_in[1];   // [4096,11008]
  const float* emb   = (const float*)d_in[2];   // [32000,4096]
  const float* Wproj = (const float*)d_in[3];   // [4096,4096]
  const float* initA = (const float*)d_in[4];   // [4096,16]
  const float* initB = (const float*)d_in[5];   // [16,11008]
  const int*   ids   = (const int*)d_in[6];     // [2,2048]
  float* outp = (float*)d_out;                  // f32 [2,2048,4096]

  char* p = (char*)d_ws;
  short* xb   = (short*)p; p += 90177536L;   // x bf16
  short* Wb   = (short*)p; p += 90177536L;   // W_base bf16
  short* Wpb  = (short*)p; p += 33554432L;   // W_proj bf16 (dead after V GEMM)
  short* shb  = (short*)p; p += 33554432L;   // shifted embeds bf16 (dead after V GEMM)
  short* Vb   = (short*)p; p += 33554432L;   // V bf16
  short* base = (short*)p; p += 33554432L;   // base_out bf16
  short* iBb  = (short*)p; p += 352256L;     // init_B bf16
  short* iAt  = (short*)p; p += 131072L;     // init_A^T bf16 [16][4096]
  float* pin  = (float*)p; p += 262144L;     // proj_in f32 [4096][16]
  float* per  = (float*)p; p += 262144L;     // proj_err f32 [4096][16]
  float* mid  = (float*)p; p += 262144L;     // mid f32 [4096][16]
  short* Aeff = (short*)p; p += 8388608L;    // [64][4096][16] bf16
  short* Beff = (short*)p; p += 22544384L;   // [64][16][11008] bf16
  // dA/dB alias Wpb+shb (live only after V GEMM): 16MB + 45MB < 64MB
  float* dA = (float*)Wpb;
  float* dB = (float*)((char*)Wpb + 16777216L);

  cvt_kernel<<<2048, 256, 0, stream>>>(x, xb, 45088768L);
  cvt_kernel<<<2048, 256, 0, stream>>>(Wbase, Wb, 45088768L);
  cvt_kernel<<<2048, 256, 0, stream>>>(Wproj, Wpb, 16777216L);
  cvt_kernel<<<86, 256, 0, stream>>>(initB, iBb, 176128L);
  tposeA_kernel<<<16, 256, 0, stream>>>(initA, iAt);
  gather_kernel<<<4096, 256, 0, stream>>>(emb, ids, shb);

  gemm8p<1><<<256, 512, 0, stream>>>(shb, Wpb, (void*)Vb, 4096, 4096, 4096);
  gemm8p<1><<<256, 512, 0, stream>>>(xb, Wb, (void*)base, 4096, 4096, 11008);

  rowgemm16<<<1024, 256, 0, stream>>>(xb, iBb, pin, 11008, 0L);   // proj_in
  rowgemm16<<<1024, 256, 0, stream>>>(Vb, iAt, per, 4096, 0L);    // proj_err

  dA_kernel<<<dim3(16, 64), 256, 0, stream>>>(Vb, pin, dA);
  dB_kernel<<<dim3(43, 64), 256, 0, stream>>>(xb, per, dB);
  scanA_kernel<<<dim3(256, 2), 256, 0, stream>>>(dA, initA, Aeff);
  scanB_kernel<<<dim3(688, 2), 256, 0, stream>>>(dB, initB, Beff);

  rowgemm16<<<1024, 256, 0, stream>>>(xb, Beff, mid, 11008, 176128L);  // mid
  final_kernel<<<4096, 256, 0, stream>>>(base, mid, Aeff, outp);
}

// Round 9
// 759.949 us; speedup vs baseline: 1.2407x; 1.1820x over previous
//
#include <hip/hip_runtime.h>

typedef __attribute__((ext_vector_type(8))) short bf16x8;
typedef __attribute__((ext_vector_type(4))) float f32x4;

__device__ __forceinline__ float b2f(short s) {
  return __uint_as_float(((unsigned int)(unsigned short)s) << 16);
}
__device__ __forceinline__ short f2b(float f) {
  unsigned int u = __float_as_uint(f);
  unsigned int r = (u + 0x7fffu + ((u >> 16) & 1u)) >> 16;
  return (short)(unsigned short)r;
}

#define GLOAD16(g, l) __builtin_amdgcn_global_load_lds( \
    (const __attribute__((address_space(1))) void*)(g),  \
    (__attribute__((address_space(3))) void*)(l), 16, 0, 0)

// ---------------- f32 -> bf16 convert ----------------
__global__ __launch_bounds__(256) void cvt_kernel(const float* __restrict__ src,
                                                  short* __restrict__ dst, long n) {
  long i = ((long)blockIdx.x * 256 + threadIdx.x) * 8;
  long stride = (long)gridDim.x * 256 * 8;
  for (; i + 8 <= n; i += stride) {
    float4 a = *(const float4*)(src + i);
    float4 b = *(const float4*)(src + i + 4);
    bf16x8 o;
    o[0] = f2b(a.x); o[1] = f2b(a.y); o[2] = f2b(a.z); o[3] = f2b(a.w);
    o[4] = f2b(b.x); o[5] = f2b(b.y); o[6] = f2b(b.z); o[7] = f2b(b.w);
    *(bf16x8*)(dst + i) = o;
  }
}

// ---------------- gather next-token embeddings, shift, convert ----------------
__global__ __launch_bounds__(256) void gather_kernel(const float* __restrict__ emb,
    const int* __restrict__ ids, short* __restrict__ sh) {
  const int token = blockIdx.x;          // 0..4095, token = b*2048 + s
  const int s = token & 2047;
  const long dst = (long)token * 4096;
  const int row = (s == 2047) ? -1 : ids[token + 1];
  for (int it = 0; it < 2; ++it) {
    const int e = it * 2048 + threadIdx.x * 8;
    bf16x8 o;
    if (row < 0) {
      #pragma unroll
      for (int j = 0; j < 8; ++j) o[j] = 0;
    } else {
      float4 a = *(const float4*)(emb + (long)row * 4096 + e);
      float4 b = *(const float4*)(emb + (long)row * 4096 + e + 4);
      o[0] = f2b(a.x); o[1] = f2b(a.y); o[2] = f2b(a.z); o[3] = f2b(a.w);
      o[4] = f2b(b.x); o[5] = f2b(b.y); o[6] = f2b(b.z); o[7] = f2b(b.w);
    }
    *(bf16x8*)(sh + dst + e) = o;
  }
}

// ---------------- init_A [4096][16] f32 -> [16][4096] bf16 ----------------
__global__ __launch_bounds__(256) void tposeA_kernel(const float* __restrict__ A,
                                                     short* __restrict__ At) {
  const int h = blockIdx.x * 256 + threadIdx.x;
  #pragma unroll
  for (int r = 0; r < 16; ++r) At[(long)r * 4096 + h] = f2b(A[(long)h * 16 + r]);
}

// ======== deep-pipelined 256x256 MFMA GEMM (r6-verified 4-phase schedule) ====
template <int OUTBF16>
__global__ __launch_bounds__(512, 2) void gemm8p(const short* __restrict__ A,
    const short* __restrict__ B, void* __restrict__ C, int M, int N, int Kd) {
  __shared__ short lds[65536];  // 128 KiB: buf{0,1} x [A 32K | B 32K]
  const int tid = threadIdx.x;
  const int lane = tid & 63;
  const int wid = tid >> 6;        // 0..7
  const int wr = wid >> 2;         // 0..1  (M half)
  const int wcn = wid & 3;         // 0..3  (N quarter)
  const int l15 = lane & 15, l4 = lane >> 4, l7 = lane & 7;
  const int lb = (lane >> 3) & 1;

  const int nbx = N >> 8;
  const int cpx = gridDim.x >> 3;
  const int wg = ((int)blockIdx.x & 7) * cpx + ((int)blockIdx.x >> 3);
  const long m0 = (long)(wg / nbx) * 256;
  const long n0 = (long)(wg % nbx) * 256;

  const int NT = Kd >> 6;

  const int rho = lane >> 3;
  const short* Ag = A + (m0 + wid * 8 + rho) * (long)Kd + (l7 ^ rho) * 8;
  const short* Bg = B + (n0 + wid * 8 + rho) * (long)Kd + (l7 ^ rho) * 8;

#define STAGE_A(b, kt, c) GLOAD16(Ag + (long)(c) * 64 * Kd + (long)(kt) * 64, \
    (char*)lds + (b) * 65536 + ((c) * 8 + wid) * 1024 + lane * 16)
#define STAGE_B(b, kt, c) GLOAD16(Bg + (long)(c) * 64 * Kd + (long)(kt) * 64, \
    (char*)lds + (b) * 65536 + 32768 + ((c) * 8 + wid) * 1024 + lane * 16)

  int aLane[2];
  #pragma unroll
  for (int h = 0; h < 2; ++h)
    aLane[h] = (lb * 64 + l7 * 8 + ((h * 4 + l4) ^ l7)) * 16;

#define READ_A(dst, buf, c)                                                   \
  do {                                                                        \
    _Pragma("unroll")                                                         \
    for (int sub = 0; sub < 2; ++sub) {                                       \
      dst[sub][0] = *(const bf16x8*)((buf) + (c) * 8192 + wr * 4096 +         \
                                     sub * 2048 + aLane[0]);                  \
      dst[sub][1] = *(const bf16x8*)((buf) + (c) * 8192 + wr * 4096 +         \
                                     sub * 2048 + aLane[1]);                  \
    }                                                                         \
  } while (0)

#define READ_B(buf)                                                           \
  do {                                                                        \
    _Pragma("unroll")                                                         \
    for (int nf = 0; nf < 4; ++nf) {                                          \
      bv[nf][0] = *(const bf16x8*)((buf) + 32768 + wcn * 8192 + nf * 2048 +   \
                                   aLane[0]);                                 \
      bv[nf][1] = *(const bf16x8*)((buf) + 32768 + wcn * 8192 + nf * 2048 +   \
                                   aLane[1]);                                 \
    }                                                                         \
  } while (0)

#define MFMA_BLOCK(q, av)                                                     \
  do {                                                                        \
    _Pragma("unroll")                                                         \
    for (int sub = 0; sub < 2; ++sub)                                         \
      _Pragma("unroll")                                                       \
      for (int nf = 0; nf < 4; ++nf) {                                        \
        acc[(q) * 2 + sub][nf] = __builtin_amdgcn_mfma_f32_16x16x32_bf16(     \
            av[sub][0], bv[nf][0], acc[(q) * 2 + sub][nf], 0, 0, 0);          \
        acc[(q) * 2 + sub][nf] = __builtin_amdgcn_mfma_f32_16x16x32_bf16(     \
            av[sub][1], bv[nf][1], acc[(q) * 2 + sub][nf], 0, 0, 0);          \
      }                                                                       \
  } while (0)

  f32x4 acc[8][4];
  #pragma unroll
  for (int m = 0; m < 8; ++m)
    #pragma unroll
    for (int n = 0; n < 4; ++n) {
      acc[m][n][0] = 0.f; acc[m][n][1] = 0.f;
      acc[m][n][2] = 0.f; acc[m][n][3] = 0.f;
    }

  // -------- prologue: tile0 (8 chunk-pairs) + tile1 chunks 0..2 --------
  STAGE_A(0, 0, 0); STAGE_B(0, 0, 0);
  STAGE_A(0, 0, 1); STAGE_B(0, 0, 1);
  STAGE_A(0, 0, 2); STAGE_B(0, 0, 2);
  STAGE_A(0, 0, 3); STAGE_B(0, 0, 3);
  STAGE_A(1, 1, 0); STAGE_B(1, 1, 0);
  STAGE_A(1, 1, 1); STAGE_B(1, 1, 1);
  STAGE_A(1, 1, 2); STAGE_B(1, 1, 2);
  asm volatile("s_waitcnt vmcnt(6)" ::: "memory");
  __builtin_amdgcn_s_barrier();
  asm volatile("" ::: "memory");

  const char* ldsb = (const char*)lds;
  bf16x8 avX[2][2], avY[2][2], bv[4][2];
  READ_B(ldsb);
  READ_A(avX, ldsb, 0);

  for (int t = 0; t < NT; ++t) {
    const int cur = t & 1;
    const int tn1 = (t + 1 < NT) ? t + 1 : 0;   // wrap -> garbage stage, safe
    const int tn2 = (t + 2 < NT) ? t + 2 : 0;
    const char* pc = ldsb + cur * 65536;
    const char* pn = ldsb + (cur ^ 1) * 65536;

    // ---- phase 0: prefetch ch1 -> avY; MFMA ch0 (avX) ----
    READ_A(avY, pc, 1);
    STAGE_A(cur ^ 1, tn1, 3); STAGE_B(cur ^ 1, tn1, 3);
    __builtin_amdgcn_s_barrier();
    asm volatile("s_waitcnt lgkmcnt(4)" ::: "memory");
    __builtin_amdgcn_sched_barrier(0);
    __builtin_amdgcn_s_setprio(1);
    MFMA_BLOCK(0, avX);
    __builtin_amdgcn_s_setprio(0);
    __builtin_amdgcn_s_barrier();
    asm volatile("" ::: "memory");

    // ---- phase 1: prefetch ch2 -> avX; MFMA ch1 (avY) ----
    READ_A(avX, pc, 2);
    STAGE_A(cur, tn2, 0); STAGE_B(cur, tn2, 0);
    __builtin_amdgcn_s_barrier();
    asm volatile("s_waitcnt lgkmcnt(4)" ::: "memory");
    __builtin_amdgcn_sched_barrier(0);
    __builtin_amdgcn_s_setprio(1);
    MFMA_BLOCK(1, avY);
    __builtin_amdgcn_s_setprio(0);
    __builtin_amdgcn_s_barrier();
    asm volatile("" ::: "memory");

    // ---- phase 2: prefetch ch3 -> avY; MFMA ch2 (avX) ----
    READ_A(avY, pc, 3);
    STAGE_A(cur, tn2, 1); STAGE_B(cur, tn2, 1);
    __builtin_amdgcn_s_barrier();
    asm volatile("s_waitcnt lgkmcnt(4)" ::: "memory");
    __builtin_amdgcn_sched_barrier(0);
    __builtin_amdgcn_s_setprio(1);
    MFMA_BLOCK(2, avX);
    __builtin_amdgcn_s_setprio(0);
    __builtin_amdgcn_s_barrier();
    asm volatile("" ::: "memory");

    // ---- phase 3: MFMA ch3 (avY); then prefetch next tile B + ch0 -> avX ----
    STAGE_A(cur, tn2, 2); STAGE_B(cur, tn2, 2);
    asm volatile("s_waitcnt vmcnt(6)" ::: "memory");
    __builtin_amdgcn_s_barrier();
    asm volatile("s_waitcnt lgkmcnt(0)" ::: "memory");
    __builtin_amdgcn_sched_barrier(0);
    __builtin_amdgcn_s_setprio(1);
    MFMA_BLOCK(3, avY);
    __builtin_amdgcn_s_setprio(0);
    __builtin_amdgcn_sched_barrier(0);
    READ_B(pn);
    READ_A(avX, pn, 0);
    __builtin_amdgcn_s_barrier();
    asm volatile("" ::: "memory");
  }
#undef STAGE_A
#undef STAGE_B
#undef READ_A
#undef READ_B
#undef MFMA_BLOCK

  // -------- epilogue: C write --------
  #pragma unroll
  for (int q = 0; q < 4; ++q)
    #pragma unroll
    for (int sub = 0; sub < 2; ++sub)
      #pragma unroll
      for (int nf = 0; nf < 4; ++nf)
        #pragma unroll
        for (int j = 0; j < 4; ++j) {
          const long row = m0 + q * 64 + wr * 32 + sub * 16 + l4 * 4 + j;
          const long col = n0 + wcn * 64 + nf * 16 + l15;
          if (OUTBF16) ((short*)C)[row * N + col] = f2b(acc[q * 2 + sub][nf][j]);
          else         ((float*)C)[row * N + col] = acc[q * 2 + sub][nf][j];
        }
}

// ======== MFMA skinny GEMM: part[ks][M][16] += A[M,k-slice] @ W[16,k-slice]^T
// BM=64 per block (= one chunk when wStride!=0), 4 waves x one 16x16 tile.
// X staged to LDS (coalesced + XOR, gemm8p pattern); W frags loaded to VGPR.
__global__ __launch_bounds__(256) void gemv16(const short* __restrict__ A,
    const short* __restrict__ W, float* __restrict__ part, int Kd, int Klen,
    long wStride) {
  __shared__ short lds[8192];   // 2 bufs x (64 rows x 64 k) bf16
  const int tid = threadIdx.x;
  const int lane = tid & 63;
  const int w = tid >> 6;                 // wave 0..3
  const int l15 = lane & 15, l4 = lane >> 4;
  const int rho = lane >> 3, j7 = lane & 7;
  const long m0 = (long)blockIdx.x * 64;
  const long k0 = (long)blockIdx.y * Klen;
  const int NTk = Klen >> 6;
  const short* Wr = W + (wStride ? (long)blockIdx.x * wStride : 0);
  const short* Ag = A + (m0 + w * 8 + rho) * (long)Kd + k0 + (j7 ^ rho) * 8;

#define STG(b, kt, i) GLOAD16(Ag + (long)(i) * 32 * Kd + (long)(kt) * 64, \
    (char*)lds + (b) * 8192 + ((i) * 4 + w) * 1024 + lane * 16)

  int aOff[2];
  #pragma unroll
  for (int kk = 0; kk < 2; ++kk)
    aOff[kk] = ((w * 16 + l15) >> 3) * 1024 + (l15 & 7) * 128 +
               (((kk * 4 + l4) ^ (l15 & 7)) * 16);

  f32x4 acc; acc[0] = 0.f; acc[1] = 0.f; acc[2] = 0.f; acc[3] = 0.f;

  STG(0, 0, 0); STG(0, 0, 1);
  for (int t = 0; t < NTk; ++t) {
    const int cur = t & 1;
    const int tn = (t + 1 < NTk) ? t + 1 : 0;
    // W loads for tile t FIRST (vmcnt queue: stage_t, W_t, stage_{t+1})
    const short* wp = Wr + (long)l15 * Kd + k0 + (long)t * 64 + l4 * 8;
    bf16x8 wv0 = *(const bf16x8*)(wp);
    bf16x8 wv1 = *(const bf16x8*)(wp + 32);
    STG(cur ^ 1, tn, 0); STG(cur ^ 1, tn, 1);
    asm volatile("s_waitcnt vmcnt(2)" ::: "memory");   // drain stage_t (+W_t)
    __builtin_amdgcn_s_barrier();
    bf16x8 a0 = *(const bf16x8*)((const char*)lds + cur * 8192 + aOff[0]);
    bf16x8 a1 = *(const bf16x8*)((const char*)lds + cur * 8192 + aOff[1]);
    asm volatile("s_waitcnt lgkmcnt(0)" ::: "memory");
    __builtin_amdgcn_sched_barrier(0);
    acc = __builtin_amdgcn_mfma_f32_16x16x32_bf16(a0, wv0, acc, 0, 0, 0);
    acc = __builtin_amdgcn_mfma_f32_16x16x32_bf16(a1, wv1, acc, 0, 0, 0);
    __builtin_amdgcn_s_barrier();
  }
#undef STG

  float* dst = part + (long)blockIdx.y * 65536;
  #pragma unroll
  for (int r = 0; r < 4; ++r)
    dst[(m0 + w * 16 + l4 * 4 + r) * 16 + l15] = acc[r];
}

// ---- sum 4 K-split partials; blockIdx.y selects (src0,dst0)/(src1,dst1) ----
__global__ __launch_bounds__(256) void reduce4_kernel(const float* __restrict__ s0,
    float* __restrict__ d0, const float* __restrict__ s1, float* __restrict__ d1) {
  const long idx = (long)blockIdx.x * 256 + threadIdx.x;
  const float* s = blockIdx.y ? s1 : s0;
  float* d = blockIdx.y ? d1 : d0;
  d[idx] = s[idx] + s[idx + 65536] + s[idx + 131072] + s[idx + 196608];
}

// ---------------- pass 1a: dA[chunk][h][r] = sum_c V[c,h]*pin[c,r] ----------------
__global__ __launch_bounds__(256) void dA_kernel(const short* __restrict__ V,
    const float* __restrict__ pin, float* __restrict__ dA) {
  const int chunk = blockIdx.y;
  const int h = blockIdx.x * 256 + threadIdx.x;
  __shared__ float ps[1024];
  #pragma unroll
  for (int i = 0; i < 4; ++i)
    ps[i * 256 + threadIdx.x] = pin[(long)chunk * 1024 + i * 256 + threadIdx.x];
  __syncthreads();
  float acc[16];
  #pragma unroll
  for (int r = 0; r < 16; ++r) acc[r] = 0.f;
  for (int c = 0; c < 64; ++c) {
    const float v = b2f(V[((long)chunk * 64 + c) * 4096 + h]);
    #pragma unroll
    for (int r = 0; r < 16; ++r) acc[r] = fmaf(v, ps[c * 16 + r], acc[r]);
  }
  float* dst = dA + ((long)chunk * 4096 + h) * 16;
  #pragma unroll
  for (int i = 0; i < 4; ++i) {
    f32x4 w; w[0] = acc[i*4]; w[1] = acc[i*4+1]; w[2] = acc[i*4+2]; w[3] = acc[i*4+3];
    *(f32x4*)(dst + i * 4) = w;
  }
}

// ---------------- pass 1b: dB[chunk][r][k] = sum_c per[c,r]*X[c,k] ----------------
__global__ __launch_bounds__(256) void dB_kernel(const short* __restrict__ X,
    const float* __restrict__ per, float* __restrict__ dB) {
  const int chunk = blockIdx.y;
  const int k = blockIdx.x * 256 + threadIdx.x;   // 43*256 == 11008
  __shared__ float ps[1024];
  #pragma unroll
  for (int i = 0; i < 4; ++i)
    ps[i * 256 + threadIdx.x] = per[(long)chunk * 1024 + i * 256 + threadIdx.x];
  __syncthreads();
  float acc[16];
  #pragma unroll
  for (int r = 0; r < 16; ++r) acc[r] = 0.f;
  for (int c = 0; c < 64; ++c) {
    const float xv = b2f(X[((long)chunk * 64 + c) * 11008 + k]);
    #pragma unroll
    for (int r = 0; r < 16; ++r) acc[r] = fmaf(xv, ps[c * 16 + r], acc[r]);
  }
  #pragma unroll
  for (int r = 0; r < 16; ++r)
    dB[((long)chunk * 16 + r) * 11008 + k] = acc[r];
}

// ---------- pass 2a: exclusive scan over chunks -> A_eff bf16 ----------
__global__ __launch_bounds__(256) void scanA_kernel(const float* __restrict__ dA,
    const float* __restrict__ initA, short* __restrict__ Aeff) {
  const int b = blockIdx.y;
  const long idx = (long)blockIdx.x * 256 + threadIdx.x;  // h*16+r, < 65536
  const float a0 = initA[idx];
  float acc = 0.f;
  for (int n = 0; n < 32; ++n) {
    const long chunk = (long)b * 32 + n;
    Aeff[chunk * 65536 + idx] = f2b(a0 - 0.02f * acc);
    acc += dA[chunk * 65536 + idx];
  }
}

// ---------- pass 2b: exclusive scan over chunks -> B_eff bf16 ----------
__global__ __launch_bounds__(256) void scanB_kernel(const float* __restrict__ dB,
    const float* __restrict__ initB, short* __restrict__ Beff) {
  const int b = blockIdx.y;
  const long idx = (long)blockIdx.x * 256 + threadIdx.x;  // r*11008+k, < 176128
  const float b0 = initB[idx];
  float acc = 0.f;
  for (int n = 0; n < 32; ++n) {
    const long chunk = (long)b * 32 + n;
    Beff[chunk * 176128 + idx] = f2b(b0 - 0.02f * acc);
    acc += dB[chunk * 176128 + idx];
  }
}

// ---------------- out(f32) = base(bf16) + 2 * mid @ A_eff^T ----------------
__global__ __launch_bounds__(256) void final_kernel(const short* __restrict__ base,
    const float* __restrict__ mid, const short* __restrict__ Aeff,
    float* __restrict__ out) {
  const int token = blockIdx.x;
  const int chunk = token >> 6;
  __shared__ float m[16];
  if (threadIdx.x < 16) m[threadIdx.x] = mid[(long)token * 16 + threadIdx.x];
  __syncthreads();
  float mf[16];
  #pragma unroll
  for (int r = 0; r < 16; ++r) mf[r] = m[r];
  for (int it = 0; it < 2; ++it) {
    const int h0 = it * 2048 + threadIdx.x * 8;
    bf16x8 bs = *(const bf16x8*)(base + (long)token * 4096 + h0);
    float res[8];
    #pragma unroll
    for (int j = 0; j < 8; ++j) {
      const short* ar = Aeff + ((long)chunk * 4096 + h0 + j) * 16;
      bf16x8 a0 = *(const bf16x8*)ar;
      bf16x8 a1 = *(const bf16x8*)(ar + 8);
      float s = 0.f;
      #pragma unroll
      for (int r = 0; r < 8; ++r) {
        s = fmaf(mf[r], b2f(a0[r]), s);
        s = fmaf(mf[r + 8], b2f(a1[r]), s);
      }
      res[j] = b2f(bs[j]) + 2.0f * s;
    }
    #pragma unroll
    for (int i = 0; i < 2; ++i) {
      f32x4 w; w[0] = res[i*4]; w[1] = res[i*4+1]; w[2] = res[i*4+2]; w[3] = res[i*4+3];
      *(f32x4*)(out + (long)token * 4096 + h0 + i * 4) = w;
    }
  }
}

extern "C" void kernel_launch(void* const* d_in, const int* in_sizes, int n_in,
                              void* d_out, int out_size, void* d_ws, size_t ws_size,
                              hipStream_t stream) {
  const float* x     = (const float*)d_in[0];   // [2,2048,11008]
  const float* Wbase = (const float*)d_in[1];   // [4096,11008]
  const float* emb   = (const float*)d_in[2];   // [32000,4096]
  const float* Wproj = (const float*)d_in[3];   // [4096,4096]
  const float* initA = (const float*)d_in[4];   // [4096,16]
  const float* initB = (const float*)d_in[5];   // [16,11008]
  const int*   ids   = (const int*)d_in[6];     // [2,2048]
  float* outp = (float*)d_out;                  // f32 [2,2048,4096]

  char* p = (char*)d_ws;
  short* xb   = (short*)p; p += 90177536L;   // x bf16
  short* Wb   = (short*)p; p += 90177536L;   // W_base bf16
  short* Wpb  = (short*)p; p += 33554432L;   // W_proj bf16 (dead after V GEMM)
  short* shb  = (short*)p; p += 33554432L;   // shifted embeds bf16 (dead after V GEMM)
  short* Vb   = (short*)p; p += 33554432L;   // V bf16
  short* base = (short*)p; p += 33554432L;   // base_out bf16
  short* iBb  = (short*)p; p += 352256L;     // init_B bf16
  short* iAt  = (short*)p; p += 131072L;     // init_A^T bf16 [16][4096]
  float* pin  = (float*)p; p += 262144L;     // proj_in f32 [4096][16]
  float* per  = (float*)p; p += 262144L;     // proj_err f32 [4096][16]
  float* mid  = (float*)p; p += 262144L;     // mid f32 [4096][16]
  short* Aeff = (short*)p; p += 8388608L;    // [64][4096][16] bf16
  short* Beff = (short*)p; p += 22544384L;   // [64][16][11008] bf16
  float* pinP = (float*)p; p += 1048576L;    // K-split partials [4][4096][16]
  float* perP = (float*)p; p += 1048576L;
  float* midP = (float*)p; p += 1048576L;
  // dA/dB alias Wpb+shb (live only after V GEMM): 16MB + 45MB < 64MB
  float* dA = (float*)Wpb;
  float* dB = (float*)((char*)Wpb + 16777216L);

  cvt_kernel<<<2048, 256, 0, stream>>>(x, xb, 45088768L);
  cvt_kernel<<<2048, 256, 0, stream>>>(Wbase, Wb, 45088768L);
  cvt_kernel<<<2048, 256, 0, stream>>>(Wproj, Wpb, 16777216L);
  cvt_kernel<<<86, 256, 0, stream>>>(initB, iBb, 176128L);
  tposeA_kernel<<<16, 256, 0, stream>>>(initA, iAt);
  gather_kernel<<<4096, 256, 0, stream>>>(emb, ids, shb);

  gemm8p<1><<<256, 512, 0, stream>>>(shb, Wpb, (void*)Vb, 4096, 4096, 4096);
  gemm8p<1><<<256, 512, 0, stream>>>(xb, Wb, (void*)base, 4096, 4096, 11008);

  gemv16<<<dim3(64, 4), 256, 0, stream>>>(xb, iBb, pinP, 11008, 2752, 0L);
  gemv16<<<dim3(64, 4), 256, 0, stream>>>(Vb, iAt, perP, 4096, 1024, 0L);
  reduce4_kernel<<<dim3(256, 2), 256, 0, stream>>>(pinP, pin, perP, per);

  dA_kernel<<<dim3(16, 64), 256, 0, stream>>>(Vb, pin, dA);
  dB_kernel<<<dim3(43, 64), 256, 0, stream>>>(xb, per, dB);
  scanA_kernel<<<dim3(256, 2), 256, 0, stream>>>(dA, initA, Aeff);
  scanB_kernel<<<dim3(688, 2), 256, 0, stream>>>(dB, initB, Beff);

  gemv16<<<dim3(64, 4), 256, 0, stream>>>(xb, Beff, midP, 11008, 2752, 176128L);
  reduce4_kernel<<<dim3(256, 1), 256, 0, stream>>>(midP, mid, midP, mid);
  final_kernel<<<4096, 256, 0, stream>>>(base, mid, Aeff, outp);
}

// Round 11
// 731.983 us; speedup vs baseline: 1.2881x; 1.0382x over previous
//
#include <hip/hip_runtime.h>

typedef __attribute__((ext_vector_type(8))) short bf16x8;
typedef __attribute__((ext_vector_type(4))) float f32x4;

__device__ __forceinline__ float b2f(short s) {
  return __uint_as_float(((unsigned int)(unsigned short)s) << 16);
}
__device__ __forceinline__ short f2b(float f) {
  unsigned int u = __float_as_uint(f);
  unsigned int r = (u + 0x7fffu + ((u >> 16) & 1u)) >> 16;
  return (short)(unsigned short)r;
}

#define GLOAD16(g, l) __builtin_amdgcn_global_load_lds( \
    (const __attribute__((address_space(1))) void*)(g),  \
    (__attribute__((address_space(3))) void*)(l), 16, 0, 0)

// ---- prep1: fused f32->bf16 convert of x, W_base, W_proj (contiguous dst) ----
__global__ __launch_bounds__(256) void prep1(const float* __restrict__ x,
    const float* __restrict__ wb, const float* __restrict__ wp,
    short* __restrict__ dst) {
  const long NX = 5636096L, NW = 11272192L, NT = 13369344L;  // vec8 items
  for (long it = (long)blockIdx.x * 256 + threadIdx.x; it < NT;
       it += (long)gridDim.x * 256) {
    const float* s; long off;
    if (it < NX)      { s = x;  off = it; }
    else if (it < NW) { s = wb; off = it - NX; }
    else              { s = wp; off = it - NW; }
    float4 a = *(const float4*)(s + off * 8);
    float4 b = *(const float4*)(s + off * 8 + 4);
    bf16x8 o;
    o[0] = f2b(a.x); o[1] = f2b(a.y); o[2] = f2b(a.z); o[3] = f2b(a.w);
    o[4] = f2b(b.x); o[5] = f2b(b.y); o[6] = f2b(b.z); o[7] = f2b(b.w);
    *(bf16x8*)(dst + it * 8) = o;
  }
}

// ---- prep2: fused initB cvt + init_A transpose + shifted-embed gather ----
__global__ __launch_bounds__(256) void prep2(const float* __restrict__ initB,
    short* __restrict__ iBb, const float* __restrict__ initA,
    short* __restrict__ iAt, const float* __restrict__ emb,
    const int* __restrict__ ids, short* __restrict__ shb) {
  const long N1 = 22016L, N2 = 26112L, NT = 2123264L;
  for (long it = (long)blockIdx.x * 256 + threadIdx.x; it < NT;
       it += (long)gridDim.x * 256) {
    if (it < N1) {                     // initB cvt, vec8
      float4 a = *(const float4*)(initB + it * 8);
      float4 b = *(const float4*)(initB + it * 8 + 4);
      bf16x8 o;
      o[0] = f2b(a.x); o[1] = f2b(a.y); o[2] = f2b(a.z); o[3] = f2b(a.w);
      o[4] = f2b(b.x); o[5] = f2b(b.y); o[6] = f2b(b.z); o[7] = f2b(b.w);
      *(bf16x8*)(iBb + it * 8) = o;
    } else if (it < N2) {              // tposeA: one h per item
      const int h = (int)(it - N1);
      #pragma unroll
      for (int r = 0; r < 16; ++r)
        iAt[(long)r * 4096 + h] = f2b(initA[(long)h * 16 + r]);
    } else {                           // gather: vec8 item
      const long i3 = it - N2;
      const int token = (int)(i3 >> 9);
      const int e = ((int)i3 & 511) * 8;
      const int s = token & 2047;
      const int row = (s == 2047) ? -1 : ids[token + 1];
      bf16x8 o;
      if (row < 0) {
        #pragma unroll
        for (int j = 0; j < 8; ++j) o[j] = 0;
      } else {
        float4 a = *(const float4*)(emb + (long)row * 4096 + e);
        float4 b = *(const float4*)(emb + (long)row * 4096 + e + 4);
        o[0] = f2b(a.x); o[1] = f2b(a.y); o[2] = f2b(a.z); o[3] = f2b(a.w);
        o[4] = f2b(b.x); o[5] = f2b(b.y); o[6] = f2b(b.z); o[7] = f2b(b.w);
      }
      *(bf16x8*)(shb + (long)token * 4096 + e) = o;
    }
  }
}

// ======== deep-pipelined 256x256 MFMA GEMM (r6-verified 4-phase schedule) ====
template <int OUTBF16>
__global__ __launch_bounds__(512, 2) void gemm8p(const short* __restrict__ A,
    const short* __restrict__ B, void* __restrict__ C, int M, int N, int Kd) {
  __shared__ short lds[65536];  // 128 KiB: buf{0,1} x [A 32K | B 32K]
  const int tid = threadIdx.x;
  const int lane = tid & 63;
  const int wid = tid >> 6;        // 0..7
  const int wr = wid >> 2;         // 0..1  (M half)
  const int wcn = wid & 3;         // 0..3  (N quarter)
  const int l15 = lane & 15, l4 = lane >> 4, l7 = lane & 7;
  const int lb = (lane >> 3) & 1;

  const int nbx = N >> 8;
  const int cpx = gridDim.x >> 3;
  const int wg = ((int)blockIdx.x & 7) * cpx + ((int)blockIdx.x >> 3);
  const long m0 = (long)(wg / nbx) * 256;
  const long n0 = (long)(wg % nbx) * 256;

  const int NT = Kd >> 6;

  const int rho = lane >> 3;
  const short* Ag = A + (m0 + wid * 8 + rho) * (long)Kd + (l7 ^ rho) * 8;
  const short* Bg = B + (n0 + wid * 8 + rho) * (long)Kd + (l7 ^ rho) * 8;

#define STAGE_A(b, kt, c) GLOAD16(Ag + (long)(c) * 64 * Kd + (long)(kt) * 64, \
    (char*)lds + (b) * 65536 + ((c) * 8 + wid) * 1024 + lane * 16)
#define STAGE_B(b, kt, c) GLOAD16(Bg + (long)(c) * 64 * Kd + (long)(kt) * 64, \
    (char*)lds + (b) * 65536 + 32768 + ((c) * 8 + wid) * 1024 + lane * 16)

  int aLane[2];
  #pragma unroll
  for (int h = 0; h < 2; ++h)
    aLane[h] = (lb * 64 + l7 * 8 + ((h * 4 + l4) ^ l7)) * 16;

#define READ_A(dst, buf, c)                                                   \
  do {                                                                        \
    _Pragma("unroll")                                                         \
    for (int sub = 0; sub < 2; ++sub) {                                       \
      dst[sub][0] = *(const bf16x8*)((buf) + (c) * 8192 + wr * 4096 +         \
                                     sub * 2048 + aLane[0]);                  \
      dst[sub][1] = *(const bf16x8*)((buf) + (c) * 8192 + wr * 4096 +         \
                                     sub * 2048 + aLane[1]);                  \
    }                                                                         \
  } while (0)

#define READ_B(buf)                                                           \
  do {                                                                        \
    _Pragma("unroll")                                                         \
    for (int nf = 0; nf < 4; ++nf) {                                          \
      bv[nf][0] = *(const bf16x8*)((buf) + 32768 + wcn * 8192 + nf * 2048 +   \
                                   aLane[0]);                                 \
      bv[nf][1] = *(const bf16x8*)((buf) + 32768 + wcn * 8192 + nf * 2048 +   \
                                   aLane[1]);                                 \
    }                                                                         \
  } while (0)

#define MFMA_BLOCK(q, av)                                                     \
  do {                                                                        \
    _Pragma("unroll")                                                         \
    for (int sub = 0; sub < 2; ++sub)                                         \
      _Pragma("unroll")                                                       \
      for (int nf = 0; nf < 4; ++nf) {                                        \
        acc[(q) * 2 + sub][nf] = __builtin_amdgcn_mfma_f32_16x16x32_bf16(     \
            av[sub][0], bv[nf][0], acc[(q) * 2 + sub][nf], 0, 0, 0);          \
        acc[(q) * 2 + sub][nf] = __builtin_amdgcn_mfma_f32_16x16x32_bf16(     \
            av[sub][1], bv[nf][1], acc[(q) * 2 + sub][nf], 0, 0, 0);          \
      }                                                                       \
  } while (0)

  f32x4 acc[8][4];
  #pragma unroll
  for (int m = 0; m < 8; ++m)
    #pragma unroll
    for (int n = 0; n < 4; ++n) {
      acc[m][n][0] = 0.f; acc[m][n][1] = 0.f;
      acc[m][n][2] = 0.f; acc[m][n][3] = 0.f;
    }

  STAGE_A(0, 0, 0); STAGE_B(0, 0, 0);
  STAGE_A(0, 0, 1); STAGE_B(0, 0, 1);
  STAGE_A(0, 0, 2); STAGE_B(0, 0, 2);
  STAGE_A(0, 0, 3); STAGE_B(0, 0, 3);
  STAGE_A(1, 1, 0); STAGE_B(1, 1, 0);
  STAGE_A(1, 1, 1); STAGE_B(1, 1, 1);
  STAGE_A(1, 1, 2); STAGE_B(1, 1, 2);
  asm volatile("s_waitcnt vmcnt(6)" ::: "memory");
  __builtin_amdgcn_s_barrier();
  asm volatile("" ::: "memory");

  const char* ldsb = (const char*)lds;
  bf16x8 avX[2][2], avY[2][2], bv[4][2];
  READ_B(ldsb);
  READ_A(avX, ldsb, 0);

  for (int t = 0; t < NT; ++t) {
    const int cur = t & 1;
    const int tn1 = (t + 1 < NT) ? t + 1 : 0;
    const int tn2 = (t + 2 < NT) ? t + 2 : 0;
    const char* pc = ldsb + cur * 65536;
    const char* pn = ldsb + (cur ^ 1) * 65536;

    READ_A(avY, pc, 1);
    STAGE_A(cur ^ 1, tn1, 3); STAGE_B(cur ^ 1, tn1, 3);
    __builtin_amdgcn_s_barrier();
    asm volatile("s_waitcnt lgkmcnt(4)" ::: "memory");
    __builtin_amdgcn_sched_barrier(0);
    __builtin_amdgcn_s_setprio(1);
    MFMA_BLOCK(0, avX);
    __builtin_amdgcn_s_setprio(0);
    __builtin_amdgcn_s_barrier();
    asm volatile("" ::: "memory");

    READ_A(avX, pc, 2);
    STAGE_A(cur, tn2, 0); STAGE_B(cur, tn2, 0);
    __builtin_amdgcn_s_barrier();
    asm volatile("s_waitcnt lgkmcnt(4)" ::: "memory");
    __builtin_amdgcn_sched_barrier(0);
    __builtin_amdgcn_s_setprio(1);
    MFMA_BLOCK(1, avY);
    __builtin_amdgcn_s_setprio(0);
    __builtin_amdgcn_s_barrier();
    asm volatile("" ::: "memory");

    READ_A(avY, pc, 3);
    STAGE_A(cur, tn2, 1); STAGE_B(cur, tn2, 1);
    __builtin_amdgcn_s_barrier();
    asm volatile("s_waitcnt lgkmcnt(4)" ::: "memory");
    __builtin_amdgcn_sched_barrier(0);
    __builtin_amdgcn_s_setprio(1);
    MFMA_BLOCK(2, avX);
    __builtin_amdgcn_s_setprio(0);
    __builtin_amdgcn_s_barrier();
    asm volatile("" ::: "memory");

    STAGE_A(cur, tn2, 2); STAGE_B(cur, tn2, 2);
    asm volatile("s_waitcnt vmcnt(6)" ::: "memory");
    __builtin_amdgcn_s_barrier();
    asm volatile("s_waitcnt lgkmcnt(0)" ::: "memory");
    __builtin_amdgcn_sched_barrier(0);
    __builtin_amdgcn_s_setprio(1);
    MFMA_BLOCK(3, avY);
    __builtin_amdgcn_s_setprio(0);
    __builtin_amdgcn_sched_barrier(0);
    READ_B(pn);
    READ_A(avX, pn, 0);
    __builtin_amdgcn_s_barrier();
    asm volatile("" ::: "memory");
  }
#undef STAGE_A
#undef STAGE_B
#undef READ_A
#undef READ_B
#undef MFMA_BLOCK

  #pragma unroll
  for (int q = 0; q < 4; ++q)
    #pragma unroll
    for (int sub = 0; sub < 2; ++sub)
      #pragma unroll
      for (int nf = 0; nf < 4; ++nf)
        #pragma unroll
        for (int j = 0; j < 4; ++j) {
          const long row = m0 + q * 64 + wr * 32 + sub * 16 + l4 * 4 + j;
          const long col = n0 + wcn * 64 + nf * 16 + l15;
          if (OUTBF16) ((short*)C)[row * N + col] = f2b(acc[q * 2 + sub][nf][j]);
          else         ((float*)C)[row * N + col] = acc[q * 2 + sub][nf][j];
        }
}

// ======== MFMA skinny GEMM core (r9-verified), callable from fused kernels ====
__device__ __forceinline__ void gemv_core(short* lds, const short* __restrict__ A,
    const short* __restrict__ W, float* __restrict__ part, int Kd, int Klen,
    long wStride) {
  const int tid = threadIdx.x;
  const int lane = tid & 63;
  const int w = tid >> 6;
  const int l15 = lane & 15, l4 = lane >> 4;
  const int rho = lane >> 3, j7 = lane & 7;
  const long m0 = (long)blockIdx.x * 64;
  const long k0 = (long)blockIdx.y * Klen;
  const int NTk = Klen >> 6;
  const short* Wr = W + (wStride ? (long)blockIdx.x * wStride : 0);
  const short* Ag = A + (m0 + w * 8 + rho) * (long)Kd + k0 + (j7 ^ rho) * 8;

#define STG(b, kt, i) GLOAD16(Ag + (long)(i) * 32 * Kd + (long)(kt) * 64, \
    (char*)lds + (b) * 8192 + ((i) * 4 + w) * 1024 + lane * 16)

  int aOff[2];
  #pragma unroll
  for (int kk = 0; kk < 2; ++kk)
    aOff[kk] = ((w * 16 + l15) >> 3) * 1024 + (l15 & 7) * 128 +
               (((kk * 4 + l4) ^ (l15 & 7)) * 16);

  f32x4 acc; acc[0] = 0.f; acc[1] = 0.f; acc[2] = 0.f; acc[3] = 0.f;

  STG(0, 0, 0); STG(0, 0, 1);
  for (int t = 0; t < NTk; ++t) {
    const int cur = t & 1;
    const int tn = (t + 1 < NTk) ? t + 1 : 0;
    const short* wp = Wr + (long)l15 * Kd + k0 + (long)t * 64 + l4 * 8;
    bf16x8 wv0 = *(const bf16x8*)(wp);
    bf16x8 wv1 = *(const bf16x8*)(wp + 32);
    STG(cur ^ 1, tn, 0); STG(cur ^ 1, tn, 1);
    asm volatile("s_waitcnt vmcnt(2)" ::: "memory");
    __builtin_amdgcn_s_barrier();
    bf16x8 a0 = *(const bf16x8*)((const char*)lds + cur * 8192 + aOff[0]);
    bf16x8 a1 = *(const bf16x8*)((const char*)lds + cur * 8192 + aOff[1]);
    asm volatile("s_waitcnt lgkmcnt(0)" ::: "memory");
    __builtin_amdgcn_sched_barrier(0);
    acc = __builtin_amdgcn_mfma_f32_16x16x32_bf16(a0, wv0, acc, 0, 0, 0);
    acc = __builtin_amdgcn_mfma_f32_16x16x32_bf16(a1, wv1, acc, 0, 0, 0);
    __builtin_amdgcn_s_barrier();
  }
#undef STG

  float* dst = part + (long)blockIdx.y * 65536;
  #pragma unroll
  for (int r = 0; r < 4; ++r)
    dst[(m0 + w * 16 + l4 * 4 + r) * 16 + l15] = acc[r];
}

// ---- pin + per in one launch (blockIdx.z selects) ----
__global__ __launch_bounds__(256) void gemv_pinper(const short* __restrict__ xb,
    const short* __restrict__ iBb, float* __restrict__ pinP,
    const short* __restrict__ Vb, const short* __restrict__ iAt,
    float* __restrict__ perP) {
  __shared__ short lds[8192];
  if (blockIdx.z == 0) gemv_core(lds, xb, iBb, pinP, 11008, 2752, 0L);
  else                 gemv_core(lds, Vb, iAt, perP, 4096, 1024, 0L);
}

// ---- mid gemv (per-chunk B_eff) ----
__global__ __launch_bounds__(256) void gemv_mid(const short* __restrict__ xb,
    const short* __restrict__ Beff, float* __restrict__ midP) {
  __shared__ short lds[8192];
  gemv_core(lds, xb, Beff, midP, 11008, 2752, 176128L);
}

// ---- fused dA + dB (partial-sum of pinP/perP folded inline) ----
__global__ __launch_bounds__(256) void dAdB_kernel(const short* __restrict__ V,
    const short* __restrict__ X, const float* __restrict__ pinP,
    const float* __restrict__ perP, float* __restrict__ dA,
    float* __restrict__ dB) {
  const int chunk = blockIdx.y;
  __shared__ float ps[1024];
  if (blockIdx.x < 16) {
    const int h = blockIdx.x * 256 + threadIdx.x;
    #pragma unroll
    for (int i = 0; i < 4; ++i) {
      const long o = (long)chunk * 1024 + i * 256 + threadIdx.x;
      ps[i * 256 + threadIdx.x] = pinP[o] + pinP[o + 65536] +
                                  pinP[o + 131072] + pinP[o + 196608];
    }
    __syncthreads();
    float acc[16];
    #pragma unroll
    for (int r = 0; r < 16; ++r) acc[r] = 0.f;
    for (int c = 0; c < 64; ++c) {
      const float v = b2f(V[((long)chunk * 64 + c) * 4096 + h]);
      #pragma unroll
      for (int r = 0; r < 16; ++r) acc[r] = fmaf(v, ps[c * 16 + r], acc[r]);
    }
    float* dst = dA + ((long)chunk * 4096 + h) * 16;
    #pragma unroll
    for (int i = 0; i < 4; ++i) {
      f32x4 w; w[0] = acc[i*4]; w[1] = acc[i*4+1]; w[2] = acc[i*4+2]; w[3] = acc[i*4+3];
      *(f32x4*)(dst + i * 4) = w;
    }
  } else {
    const int k = (blockIdx.x - 16) * 256 + threadIdx.x;  // 43*256 == 11008
    #pragma unroll
    for (int i = 0; i < 4; ++i) {
      const long o = (long)chunk * 1024 + i * 256 + threadIdx.x;
      ps[i * 256 + threadIdx.x] = perP[o] + perP[o + 65536] +
                                  perP[o + 131072] + perP[o + 196608];
    }
    __syncthreads();
    float acc[16];
    #pragma unroll
    for (int r = 0; r < 16; ++r) acc[r] = 0.f;
    for (int c = 0; c < 64; ++c) {
      const float xv = b2f(X[((long)chunk * 64 + c) * 11008 + k]);
      #pragma unroll
      for (int r = 0; r < 16; ++r) acc[r] = fmaf(xv, ps[c * 16 + r], acc[r]);
    }
    #pragma unroll
    for (int r = 0; r < 16; ++r)
      dB[((long)chunk * 16 + r) * 11008 + k] = acc[r];
  }
}

// ---- fused exclusive scans -> A_eff, B_eff (bf16) ----
__global__ __launch_bounds__(256) void scan_kernel(const float* __restrict__ dA,
    const float* __restrict__ initA, short* __restrict__ Aeff,
    const float* __restrict__ dB, const float* __restrict__ initB,
    short* __restrict__ Beff) {
  const int b = blockIdx.y;
  if (blockIdx.x < 256) {
    const long idx = (long)blockIdx.x * 256 + threadIdx.x;  // < 65536
    const float a0 = initA[idx];
    float acc = 0.f;
    for (int n = 0; n < 32; ++n) {
      const long chunk = (long)b * 32 + n;
      Aeff[chunk * 65536 + idx] = f2b(a0 - 0.02f * acc);
      acc += dA[chunk * 65536 + idx];
    }
  } else {
    const long idx = (long)(blockIdx.x - 256) * 256 + threadIdx.x;  // < 176128
    const float b0 = initB[idx];
    float acc = 0.f;
    for (int n = 0; n < 32; ++n) {
      const long chunk = (long)b * 32 + n;
      Beff[chunk * 176128 + idx] = f2b(b0 - 0.02f * acc);
      acc += dB[chunk * 176128 + idx];
    }
  }
}

// ---- out(f32) = base(bf16) + 2 * mid @ A_eff^T (midP partials summed inline) ----
__global__ __launch_bounds__(256) void final_kernel(const short* __restrict__ base,
    const float* __restrict__ midP, const short* __restrict__ Aeff,
    float* __restrict__ out) {
  const int token = blockIdx.x;
  const int chunk = token >> 6;
  __shared__ float m[16];
  if (threadIdx.x < 16) {
    const long o = (long)token * 16 + threadIdx.x;
    m[threadIdx.x] = midP[o] + midP[o + 65536] + midP[o + 131072] + midP[o + 196608];
  }
  __syncthreads();
  float mf[16];
  #pragma unroll
  for (int r = 0; r < 16; ++r) mf[r] = m[r];
  for (int it = 0; it < 2; ++it) {
    const int h0 = it * 2048 + threadIdx.x * 8;
    bf16x8 bs = *(const bf16x8*)(base + (long)token * 4096 + h0);
    float res[8];
    #pragma unroll
    for (int j = 0; j < 8; ++j) {
      const short* ar = Aeff + ((long)chunk * 4096 + h0 + j) * 16;
      bf16x8 a0 = *(const bf16x8*)ar;
      bf16x8 a1 = *(const bf16x8*)(ar + 8);
      float s = 0.f;
      #pragma unroll
      for (int r = 0; r < 8; ++r) {
        s = fmaf(mf[r], b2f(a0[r]), s);
        s = fmaf(mf[r + 8], b2f(a1[r]), s);
      }
      res[j] = b2f(bs[j]) + 2.0f * s;
    }
    #pragma unroll
    for (int i = 0; i < 2; ++i) {
      f32x4 w; w[0] = res[i*4]; w[1] = res[i*4+1]; w[2] = res[i*4+2]; w[3] = res[i*4+3];
      *(f32x4*)(out + (long)token * 4096 + h0 + i * 4) = w;
    }
  }
}

extern "C" void kernel_launch(void* const* d_in, const int* in_sizes, int n_in,
                              void* d_out, int out_size, void* d_ws, size_t ws_size,
                              hipStream_t stream) {
  const float* x     = (const float*)d_in[0];   // [2,2048,11008]
  const float* Wbase = (const float*)d_in[1];   // [4096,11008]
  const float* emb   = (const float*)d_in[2];   // [32000,4096]
  const float* Wproj = (const float*)d_in[3];   // [4096,4096]
  const float* initA = (const float*)d_in[4];   // [4096,16]
  const float* initB = (const float*)d_in[5];   // [16,11008]
  const int*   ids   = (const int*)d_in[6];     // [2,2048]
  float* outp = (float*)d_out;                  // f32 [2,2048,4096]

  char* p = (char*)d_ws;
  short* xb   = (short*)p; p += 90177536L;   // x bf16            (prep1 seg 0)
  short* Wb   = (short*)p; p += 90177536L;   // W_base bf16       (prep1 seg 1)
  short* Wpb  = (short*)p; p += 33554432L;   // W_proj bf16       (prep1 seg 2)
  short* shb  = (short*)p; p += 33554432L;   // shifted embeds bf16
  short* Vb   = (short*)p; p += 33554432L;   // V bf16
  short* base = (short*)p; p += 33554432L;   // base_out bf16
  short* iBb  = (short*)p; p += 352256L;     // init_B bf16
  short* iAt  = (short*)p; p += 131072L;     // init_A^T bf16 [16][4096]
  short* Aeff = (short*)p; p += 8388608L;    // [64][4096][16] bf16
  short* Beff = (short*)p; p += 22544384L;   // [64][16][11008] bf16
  float* pinP = (float*)p; p += 1048576L;    // K-split partials [4][4096][16]
  float* perP = (float*)p; p += 1048576L;
  float* midP = (float*)p; p += 1048576L;
  // dA/dB alias Wpb+shb (live only after V GEMM): 16MB + 45MB < 64MB
  float* dA = (float*)Wpb;
  float* dB = (float*)((char*)Wpb + 16777216L);

  prep1<<<2048, 256, 0, stream>>>(x, Wbase, Wproj, xb);
  prep2<<<2048, 256, 0, stream>>>(initB, iBb, initA, iAt, emb, ids, shb);

  gemm8p<1><<<256, 512, 0, stream>>>(shb, Wpb, (void*)Vb, 4096, 4096, 4096);
  gemm8p<1><<<256, 512, 0, stream>>>(xb, Wb, (void*)base, 4096, 4096, 11008);

  gemv_pinper<<<dim3(64, 4, 2), 256, 0, stream>>>(xb, iBb, pinP, Vb, iAt, perP);
  dAdB_kernel<<<dim3(59, 64), 256, 0, stream>>>(Vb, xb, pinP, perP, dA, dB);
  scan_kernel<<<dim3(944, 2), 256, 0, stream>>>(dA, initA, Aeff, dB, initB, Beff);

  gemv_mid<<<dim3(64, 4), 256, 0, stream>>>(xb, Beff, midP);
  final_kernel<<<4096, 256, 0, stream>>>(base, midP, Aeff, outp);
}

// Round 12
// 669.518 us; speedup vs baseline: 1.4083x; 1.0933x over previous
//
#include <hip/hip_runtime.h>

typedef __attribute__((ext_vector_type(8))) short bf16x8;
typedef __attribute__((ext_vector_type(4))) float f32x4;

__device__ __forceinline__ float b2f(short s) {
  return __uint_as_float(((unsigned int)(unsigned short)s) << 16);
}
__device__ __forceinline__ short f2b(float f) {
  unsigned int u = __float_as_uint(f);
  unsigned int r = (u + 0x7fffu + ((u >> 16) & 1u)) >> 16;
  return (short)(unsigned short)r;
}

#define GLOAD16(g, l) __builtin_amdgcn_global_load_lds( \
    (const __attribute__((address_space(1))) void*)(g),  \
    (__attribute__((address_space(3))) void*)(l), 16, 0, 0)

// ---- prep1: fused f32->bf16 convert of x, W_base, W_proj (contiguous dst) ----
__global__ __launch_bounds__(256) void prep1(const float* __restrict__ x,
    const float* __restrict__ wb, const float* __restrict__ wp,
    short* __restrict__ dst) {
  const long NX = 5636096L, NW = 11272192L, NT = 13369344L;  // vec8 items
  for (long it = (long)blockIdx.x * 256 + threadIdx.x; it < NT;
       it += (long)gridDim.x * 256) {
    const float* s; long off;
    if (it < NX)      { s = x;  off = it; }
    else if (it < NW) { s = wb; off = it - NX; }
    else              { s = wp; off = it - NW; }
    float4 a = *(const float4*)(s + off * 8);
    float4 b = *(const float4*)(s + off * 8 + 4);
    bf16x8 o;
    o[0] = f2b(a.x); o[1] = f2b(a.y); o[2] = f2b(a.z); o[3] = f2b(a.w);
    o[4] = f2b(b.x); o[5] = f2b(b.y); o[6] = f2b(b.z); o[7] = f2b(b.w);
    *(bf16x8*)(dst + it * 8) = o;
  }
}

// ---- prep2: fused initB cvt + init_A transpose + shifted-embed gather ----
__global__ __launch_bounds__(256) void prep2(const float* __restrict__ initB,
    short* __restrict__ iBb, const float* __restrict__ initA,
    short* __restrict__ iAt, const float* __restrict__ emb,
    const int* __restrict__ ids, short* __restrict__ shb) {
  const long N1 = 22016L, N2 = 26112L, NT = 2123264L;
  for (long it = (long)blockIdx.x * 256 + threadIdx.x; it < NT;
       it += (long)gridDim.x * 256) {
    if (it < N1) {                     // initB cvt, vec8
      float4 a = *(const float4*)(initB + it * 8);
      float4 b = *(const float4*)(initB + it * 8 + 4);
      bf16x8 o;
      o[0] = f2b(a.x); o[1] = f2b(a.y); o[2] = f2b(a.z); o[3] = f2b(a.w);
      o[4] = f2b(b.x); o[5] = f2b(b.y); o[6] = f2b(b.z); o[7] = f2b(b.w);
      *(bf16x8*)(iBb + it * 8) = o;
    } else if (it < N2) {              // tposeA: one h per item
      const int h = (int)(it - N1);
      #pragma unroll
      for (int r = 0; r < 16; ++r)
        iAt[(long)r * 4096 + h] = f2b(initA[(long)h * 16 + r]);
    } else {                           // gather: vec8 item
      const long i3 = it - N2;
      const int token = (int)(i3 >> 9);
      const int e = ((int)i3 & 511) * 8;
      const int s = token & 2047;
      const int row = (s == 2047) ? -1 : ids[token + 1];
      bf16x8 o;
      if (row < 0) {
        #pragma unroll
        for (int j = 0; j < 8; ++j) o[j] = 0;
      } else {
        float4 a = *(const float4*)(emb + (long)row * 4096 + e);
        float4 b = *(const float4*)(emb + (long)row * 4096 + e + 4);
        o[0] = f2b(a.x); o[1] = f2b(a.y); o[2] = f2b(a.z); o[3] = f2b(a.w);
        o[4] = f2b(b.x); o[5] = f2b(b.y); o[6] = f2b(b.z); o[7] = f2b(b.w);
      }
      *(bf16x8*)(shb + (long)token * 4096 + e) = o;
    }
  }
}

// ======== deep-pipelined 256x256 MFMA GEMM (r6-verified 4-phase schedule) ====
// FUSE=0: C = bf16 store (V GEMM). FUSE=1: epilogue computes
// out(f32) = acc + 2 * mid[row] . Aeff[chunk][col]  (LoRA add fused; mid =
// sum of 4 K-split partials staged into the freed LDS).
template <int FUSE>
__global__ __launch_bounds__(512, 2) void gemm8p(const short* __restrict__ A,
    const short* __restrict__ B, void* __restrict__ C,
    const float* __restrict__ midP, const short* __restrict__ Aeff,
    int M, int N, int Kd) {
  __shared__ short lds[65536];  // 128 KiB: buf{0,1} x [A 32K | B 32K]
  const int tid = threadIdx.x;
  const int lane = tid & 63;
  const int wid = tid >> 6;        // 0..7
  const int wr = wid >> 2;         // 0..1  (M half)
  const int wcn = wid & 3;         // 0..3  (N quarter)
  const int l15 = lane & 15, l4 = lane >> 4, l7 = lane & 7;
  const int lb = (lane >> 3) & 1;

  const int nbx = N >> 8;
  const int cpx = gridDim.x >> 3;
  const int wg = ((int)blockIdx.x & 7) * cpx + ((int)blockIdx.x >> 3);
  const long m0 = (long)(wg / nbx) * 256;
  const long n0 = (long)(wg % nbx) * 256;

  const int NT = Kd >> 6;

  const int rho = lane >> 3;
  const short* Ag = A + (m0 + wid * 8 + rho) * (long)Kd + (l7 ^ rho) * 8;
  const short* Bg = B + (n0 + wid * 8 + rho) * (long)Kd + (l7 ^ rho) * 8;

#define STAGE_A(b, kt, c) GLOAD16(Ag + (long)(c) * 64 * Kd + (long)(kt) * 64, \
    (char*)lds + (b) * 65536 + ((c) * 8 + wid) * 1024 + lane * 16)
#define STAGE_B(b, kt, c) GLOAD16(Bg + (long)(c) * 64 * Kd + (long)(kt) * 64, \
    (char*)lds + (b) * 65536 + 32768 + ((c) * 8 + wid) * 1024 + lane * 16)

  int aLane[2];
  #pragma unroll
  for (int h = 0; h < 2; ++h)
    aLane[h] = (lb * 64 + l7 * 8 + ((h * 4 + l4) ^ l7)) * 16;

#define READ_A(dst, buf, c)                                                   \
  do {                                                                        \
    _Pragma("unroll")                                                         \
    for (int sub = 0; sub < 2; ++sub) {                                       \
      dst[sub][0] = *(const bf16x8*)((buf) + (c) * 8192 + wr * 4096 +         \
                                     sub * 2048 + aLane[0]);                  \
      dst[sub][1] = *(const bf16x8*)((buf) + (c) * 8192 + wr * 4096 +         \
                                     sub * 2048 + aLane[1]);                  \
    }                                                                         \
  } while (0)

#define READ_B(buf)                                                           \
  do {                                                                        \
    _Pragma("unroll")                                                         \
    for (int nf = 0; nf < 4; ++nf) {                                          \
      bv[nf][0] = *(const bf16x8*)((buf) + 32768 + wcn * 8192 + nf * 2048 +   \
                                   aLane[0]);                                 \
      bv[nf][1] = *(const bf16x8*)((buf) + 32768 + wcn * 8192 + nf * 2048 +   \
                                   aLane[1]);                                 \
    }                                                                         \
  } while (0)

#define MFMA_BLOCK(q, av)                                                     \
  do {                                                                        \
    _Pragma("unroll")                                                         \
    for (int sub = 0; sub < 2; ++sub)                                         \
      _Pragma("unroll")                                                       \
      for (int nf = 0; nf < 4; ++nf) {                                        \
        acc[(q) * 2 + sub][nf] = __builtin_amdgcn_mfma_f32_16x16x32_bf16(     \
            av[sub][0], bv[nf][0], acc[(q) * 2 + sub][nf], 0, 0, 0);          \
        acc[(q) * 2 + sub][nf] = __builtin_amdgcn_mfma_f32_16x16x32_bf16(     \
            av[sub][1], bv[nf][1], acc[(q) * 2 + sub][nf], 0, 0, 0);          \
      }                                                                       \
  } while (0)

  f32x4 acc[8][4];
  #pragma unroll
  for (int m = 0; m < 8; ++m)
    #pragma unroll
    for (int n = 0; n < 4; ++n) {
      acc[m][n][0] = 0.f; acc[m][n][1] = 0.f;
      acc[m][n][2] = 0.f; acc[m][n][3] = 0.f;
    }

  STAGE_A(0, 0, 0); STAGE_B(0, 0, 0);
  STAGE_A(0, 0, 1); STAGE_B(0, 0, 1);
  STAGE_A(0, 0, 2); STAGE_B(0, 0, 2);
  STAGE_A(0, 0, 3); STAGE_B(0, 0, 3);
  STAGE_A(1, 1, 0); STAGE_B(1, 1, 0);
  STAGE_A(1, 1, 1); STAGE_B(1, 1, 1);
  STAGE_A(1, 1, 2); STAGE_B(1, 1, 2);
  asm volatile("s_waitcnt vmcnt(6)" ::: "memory");
  __builtin_amdgcn_s_barrier();
  asm volatile("" ::: "memory");

  const char* ldsb = (const char*)lds;
  bf16x8 avX[2][2], avY[2][2], bv[4][2];
  READ_B(ldsb);
  READ_A(avX, ldsb, 0);

  for (int t = 0; t < NT; ++t) {
    const int cur = t & 1;
    const int tn1 = (t + 1 < NT) ? t + 1 : 0;
    const int tn2 = (t + 2 < NT) ? t + 2 : 0;
    const char* pc = ldsb + cur * 65536;
    const char* pn = ldsb + (cur ^ 1) * 65536;

    READ_A(avY, pc, 1);
    STAGE_A(cur ^ 1, tn1, 3); STAGE_B(cur ^ 1, tn1, 3);
    __builtin_amdgcn_s_barrier();
    asm volatile("s_waitcnt lgkmcnt(4)" ::: "memory");
    __builtin_amdgcn_sched_barrier(0);
    __builtin_amdgcn_s_setprio(1);
    MFMA_BLOCK(0, avX);
    __builtin_amdgcn_s_setprio(0);
    __builtin_amdgcn_s_barrier();
    asm volatile("" ::: "memory");

    READ_A(avX, pc, 2);
    STAGE_A(cur, tn2, 0); STAGE_B(cur, tn2, 0);
    __builtin_amdgcn_s_barrier();
    asm volatile("s_waitcnt lgkmcnt(4)" ::: "memory");
    __builtin_amdgcn_sched_barrier(0);
    __builtin_amdgcn_s_setprio(1);
    MFMA_BLOCK(1, avY);
    __builtin_amdgcn_s_setprio(0);
    __builtin_amdgcn_s_barrier();
    asm volatile("" ::: "memory");

    READ_A(avY, pc, 3);
    STAGE_A(cur, tn2, 1); STAGE_B(cur, tn2, 1);
    __builtin_amdgcn_s_barrier();
    asm volatile("s_waitcnt lgkmcnt(4)" ::: "memory");
    __builtin_amdgcn_sched_barrier(0);
    __builtin_amdgcn_s_setprio(1);
    MFMA_BLOCK(2, avX);
    __builtin_amdgcn_s_setprio(0);
    __builtin_amdgcn_s_barrier();
    asm volatile("" ::: "memory");

    STAGE_A(cur, tn2, 2); STAGE_B(cur, tn2, 2);
    asm volatile("s_waitcnt vmcnt(6)" ::: "memory");
    __builtin_amdgcn_s_barrier();
    asm volatile("s_waitcnt lgkmcnt(0)" ::: "memory");
    __builtin_amdgcn_sched_barrier(0);
    __builtin_amdgcn_s_setprio(1);
    MFMA_BLOCK(3, avY);
    __builtin_amdgcn_s_setprio(0);
    __builtin_amdgcn_sched_barrier(0);
    READ_B(pn);
    READ_A(avX, pn, 0);
    __builtin_amdgcn_s_barrier();
    asm volatile("" ::: "memory");
  }
#undef STAGE_A
#undef STAGE_B
#undef READ_A
#undef READ_B
#undef MFMA_BLOCK

  if (FUSE) {
    // drain in-flight wrap-garbage global_load_lds before reusing LDS
    asm volatile("s_waitcnt vmcnt(0) lgkmcnt(0)" ::: "memory");
    __builtin_amdgcn_s_barrier();
    float* mlds = (float*)lds;   // mid[256 rows][16] = 16 KiB
    {
      const long o0 = m0 * 16 + tid * 8;
      #pragma unroll
      for (int half = 0; half < 2; ++half) {
        f32x4 v;
        v[0] = 0.f; v[1] = 0.f; v[2] = 0.f; v[3] = 0.f;
        #pragma unroll
        for (int s = 0; s < 4; ++s) {
          f32x4 tv = *(const f32x4*)(midP + o0 + half * 4 + (long)s * 65536);
          v[0] += tv[0]; v[1] += tv[1]; v[2] += tv[2]; v[3] += tv[3];
        }
        *(f32x4*)(mlds + tid * 8 + half * 4) = v;
      }
    }
    __builtin_amdgcn_s_barrier();
    const long chunk0 = m0 >> 6;
    float* out = (float*)C;
    #pragma unroll
    for (int q = 0; q < 4; ++q) {
      float af[4][16];
      #pragma unroll
      for (int nf = 0; nf < 4; ++nf) {
        const long col = n0 + wcn * 64 + nf * 16 + l15;
        const short* ap = Aeff + ((chunk0 + q) * 4096 + col) * 16;
        bf16x8 a0 = *(const bf16x8*)ap;
        bf16x8 a1 = *(const bf16x8*)(ap + 8);
        #pragma unroll
        for (int r = 0; r < 8; ++r) {
          af[nf][r] = b2f(a0[r]);
          af[nf][r + 8] = b2f(a1[r]);
        }
      }
      #pragma unroll
      for (int sub = 0; sub < 2; ++sub)
        #pragma unroll
        for (int j = 0; j < 4; ++j) {
          const int rl = q * 64 + wr * 32 + sub * 16 + l4 * 4 + j;
          float mf[16];
          #pragma unroll
          for (int hh = 0; hh < 4; ++hh) {
            f32x4 mv = *(const f32x4*)(mlds + rl * 16 + hh * 4);
            mf[hh * 4] = mv[0]; mf[hh * 4 + 1] = mv[1];
            mf[hh * 4 + 2] = mv[2]; mf[hh * 4 + 3] = mv[3];
          }
          #pragma unroll
          for (int nf = 0; nf < 4; ++nf) {
            float s = 0.f;
            #pragma unroll
            for (int r = 0; r < 16; ++r) s = fmaf(mf[r], af[nf][r], s);
            const long col = n0 + wcn * 64 + nf * 16 + l15;
            out[(m0 + rl) * N + col] = acc[q * 2 + sub][nf][j] + 2.0f * s;
          }
        }
    }
  } else {
    #pragma unroll
    for (int q = 0; q < 4; ++q)
      #pragma unroll
      for (int sub = 0; sub < 2; ++sub)
        #pragma unroll
        for (int nf = 0; nf < 4; ++nf)
          #pragma unroll
          for (int j = 0; j < 4; ++j) {
            const long row = m0 + q * 64 + wr * 32 + sub * 16 + l4 * 4 + j;
            const long col = n0 + wcn * 64 + nf * 16 + l15;
            ((short*)C)[row * N + col] = f2b(acc[q * 2 + sub][nf][j]);
          }
  }
}

// ======== MFMA skinny GEMM core (r9-verified), callable from fused kernels ====
__device__ __forceinline__ void gemv_core(short* lds, const short* __restrict__ A,
    const short* __restrict__ W, float* __restrict__ part, int Kd, int Klen,
    long wStride) {
  const int tid = threadIdx.x;
  const int lane = tid & 63;
  const int w = tid >> 6;
  const int l15 = lane & 15, l4 = lane >> 4;
  const int rho = lane >> 3, j7 = lane & 7;
  const long m0 = (long)blockIdx.x * 64;
  const long k0 = (long)blockIdx.y * Klen;
  const int NTk = Klen >> 6;
  const short* Wr = W + (wStride ? (long)blockIdx.x * wStride : 0);
  const short* Ag = A + (m0 + w * 8 + rho) * (long)Kd + k0 + (j7 ^ rho) * 8;

#define STG(b, kt, i) GLOAD16(Ag + (long)(i) * 32 * Kd + (long)(kt) * 64, \
    (char*)lds + (b) * 8192 + ((i) * 4 + w) * 1024 + lane * 16)

  int aOff[2];
  #pragma unroll
  for (int kk = 0; kk < 2; ++kk)
    aOff[kk] = ((w * 16 + l15) >> 3) * 1024 + (l15 & 7) * 128 +
               (((kk * 4 + l4) ^ (l15 & 7)) * 16);

  f32x4 acc; acc[0] = 0.f; acc[1] = 0.f; acc[2] = 0.f; acc[3] = 0.f;

  STG(0, 0, 0); STG(0, 0, 1);
  for (int t = 0; t < NTk; ++t) {
    const int cur = t & 1;
    const int tn = (t + 1 < NTk) ? t + 1 : 0;
    const short* wp = Wr + (long)l15 * Kd + k0 + (long)t * 64 + l4 * 8;
    bf16x8 wv0 = *(const bf16x8*)(wp);
    bf16x8 wv1 = *(const bf16x8*)(wp + 32);
    STG(cur ^ 1, tn, 0); STG(cur ^ 1, tn, 1);
    asm volatile("s_waitcnt vmcnt(2)" ::: "memory");
    __builtin_amdgcn_s_barrier();
    bf16x8 a0 = *(const bf16x8*)((const char*)lds + cur * 8192 + aOff[0]);
    bf16x8 a1 = *(const bf16x8*)((const char*)lds + cur * 8192 + aOff[1]);
    asm volatile("s_waitcnt lgkmcnt(0)" ::: "memory");
    __builtin_amdgcn_sched_barrier(0);
    acc = __builtin_amdgcn_mfma_f32_16x16x32_bf16(a0, wv0, acc, 0, 0, 0);
    acc = __builtin_amdgcn_mfma_f32_16x16x32_bf16(a1, wv1, acc, 0, 0, 0);
    __builtin_amdgcn_s_barrier();
  }
#undef STG

  float* dst = part + (long)blockIdx.y * 65536;
  #pragma unroll
  for (int r = 0; r < 4; ++r)
    dst[(m0 + w * 16 + l4 * 4 + r) * 16 + l15] = acc[r];
}

// ---- pin + per in one launch (blockIdx.z selects) ----
__global__ __launch_bounds__(256) void gemv_pinper(const short* __restrict__ xb,
    const short* __restrict__ iBb, float* __restrict__ pinP,
    const short* __restrict__ Vb, const short* __restrict__ iAt,
    float* __restrict__ perP) {
  __shared__ short lds[8192];
  if (blockIdx.z == 0) gemv_core(lds, xb, iBb, pinP, 11008, 2752, 0L);
  else                 gemv_core(lds, Vb, iAt, perP, 4096, 1024, 0L);
}

// ---- mid gemv (per-chunk B_eff) ----
__global__ __launch_bounds__(256) void gemv_mid(const short* __restrict__ xb,
    const short* __restrict__ Beff, float* __restrict__ midP) {
  __shared__ short lds[8192];
  gemv_core(lds, xb, Beff, midP, 11008, 2752, 176128L);
}

// ---- fused dA + dB (partial-sum of pinP/perP folded inline) ----
__global__ __launch_bounds__(256) void dAdB_kernel(const short* __restrict__ V,
    const short* __restrict__ X, const float* __restrict__ pinP,
    const float* __restrict__ perP, float* __restrict__ dA,
    float* __restrict__ dB) {
  const int chunk = blockIdx.y;
  __shared__ float ps[1024];
  if (blockIdx.x < 16) {
    const int h = blockIdx.x * 256 + threadIdx.x;
    #pragma unroll
    for (int i = 0; i < 4; ++i) {
      const long o = (long)chunk * 1024 + i * 256 + threadIdx.x;
      ps[i * 256 + threadIdx.x] = pinP[o] + pinP[o + 65536] +
                                  pinP[o + 131072] + pinP[o + 196608];
    }
    __syncthreads();
    float acc[16];
    #pragma unroll
    for (int r = 0; r < 16; ++r) acc[r] = 0.f;
    for (int c = 0; c < 64; ++c) {
      const float v = b2f(V[((long)chunk * 64 + c) * 4096 + h]);
      #pragma unroll
      for (int r = 0; r < 16; ++r) acc[r] = fmaf(v, ps[c * 16 + r], acc[r]);
    }
    float* dst = dA + ((long)chunk * 4096 + h) * 16;
    #pragma unroll
    for (int i = 0; i < 4; ++i) {
      f32x4 w; w[0] = acc[i*4]; w[1] = acc[i*4+1]; w[2] = acc[i*4+2]; w[3] = acc[i*4+3];
      *(f32x4*)(dst + i * 4) = w;
    }
  } else {
    const int k = (blockIdx.x - 16) * 256 + threadIdx.x;  // 43*256 == 11008
    #pragma unroll
    for (int i = 0; i < 4; ++i) {
      const long o = (long)chunk * 1024 + i * 256 + threadIdx.x;
      ps[i * 256 + threadIdx.x] = perP[o] + perP[o + 65536] +
                                  perP[o + 131072] + perP[o + 196608];
    }
    __syncthreads();
    float acc[16];
    #pragma unroll
    for (int r = 0; r < 16; ++r) acc[r] = 0.f;
    for (int c = 0; c < 64; ++c) {
      const float xv = b2f(X[((long)chunk * 64 + c) * 11008 + k]);
      #pragma unroll
      for (int r = 0; r < 16; ++r) acc[r] = fmaf(xv, ps[c * 16 + r], acc[r]);
    }
    #pragma unroll
    for (int r = 0; r < 16; ++r)
      dB[((long)chunk * 16 + r) * 11008 + k] = acc[r];
  }
}

// ---- fused exclusive scans -> A_eff, B_eff (bf16) ----
__global__ __launch_bounds__(256) void scan_kernel(const float* __restrict__ dA,
    const float* __restrict__ initA, short* __restrict__ Aeff,
    const float* __restrict__ dB, const float* __restrict__ initB,
    short* __restrict__ Beff) {
  const int b = blockIdx.y;
  if (blockIdx.x < 256) {
    const long idx = (long)blockIdx.x * 256 + threadIdx.x;  // < 65536
    const float a0 = initA[idx];
    float acc = 0.f;
    for (int n = 0; n < 32; ++n) {
      const long chunk = (long)b * 32 + n;
      Aeff[chunk * 65536 + idx] = f2b(a0 - 0.02f * acc);
      acc += dA[chunk * 65536 + idx];
    }
  } else {
    const long idx = (long)(blockIdx.x - 256) * 256 + threadIdx.x;  // < 176128
    const float b0 = initB[idx];
    float acc = 0.f;
    for (int n = 0; n < 32; ++n) {
      const long chunk = (long)b * 32 + n;
      Beff[chunk * 176128 + idx] = f2b(b0 - 0.02f * acc);
      acc += dB[chunk * 176128 + idx];
    }
  }
}

extern "C" void kernel_launch(void* const* d_in, const int* in_sizes, int n_in,
                              void* d_out, int out_size, void* d_ws, size_t ws_size,
                              hipStream_t stream) {
  const float* x     = (const float*)d_in[0];   // [2,2048,11008]
  const float* Wbase = (const float*)d_in[1];   // [4096,11008]
  const float* emb   = (const float*)d_in[2];   // [32000,4096]
  const float* Wproj = (const float*)d_in[3];   // [4096,4096]
  const float* initA = (const float*)d_in[4];   // [4096,16]
  const float* initB = (const float*)d_in[5];   // [16,11008]
  const int*   ids   = (const int*)d_in[6];     // [2,2048]
  float* outp = (float*)d_out;                  // f32 [2,2048,4096]

  char* p = (char*)d_ws;
  short* xb   = (short*)p; p += 90177536L;   // x bf16            (prep1 seg 0)
  short* Wb   = (short*)p; p += 90177536L;   // W_base bf16       (prep1 seg 1)
  short* Wpb  = (short*)p; p += 33554432L;   // W_proj bf16       (prep1 seg 2)
  short* shb  = (short*)p; p += 33554432L;   // shifted embeds bf16
  short* Vb   = (short*)p; p += 33554432L;   // V bf16
  short* iBb  = (short*)p; p += 352256L;     // init_B bf16
  short* iAt  = (short*)p; p += 131072L;     // init_A^T bf16 [16][4096]
  short* Aeff = (short*)p; p += 8388608L;    // [64][4096][16] bf16
  short* Beff = (short*)p; p += 22544384L;   // [64][16][11008] bf16
  float* pinP = (float*)p; p += 1048576L;    // K-split partials [4][4096][16]
  float* perP = (float*)p; p += 1048576L;
  float* midP = (float*)p; p += 1048576L;
  // dA/dB alias Wpb+shb (live only after V GEMM): 16MB + 45MB < 64MB
  float* dA = (float*)Wpb;
  float* dB = (float*)((char*)Wpb + 16777216L);

  prep1<<<2048, 256, 0, stream>>>(x, Wbase, Wproj, xb);
  prep2<<<2048, 256, 0, stream>>>(initB, iBb, initA, iAt, emb, ids, shb);

  // V = shifted_embeds @ W_proj^T  (bf16 out)
  gemm8p<0><<<256, 512, 0, stream>>>(shb, Wpb, (void*)Vb, nullptr, nullptr,
                                     4096, 4096, 4096);

  // fast-weight chain (independent of base GEMM)
  gemv_pinper<<<dim3(64, 4, 2), 256, 0, stream>>>(xb, iBb, pinP, Vb, iAt, perP);
  dAdB_kernel<<<dim3(59, 64), 256, 0, stream>>>(Vb, xb, pinP, perP, dA, dB);
  scan_kernel<<<dim3(944, 2), 256, 0, stream>>>(dA, initA, Aeff, dB, initB, Beff);
  gemv_mid<<<dim3(64, 4), 256, 0, stream>>>(xb, Beff, midP);

  // base GEMM with fused LoRA epilogue -> final f32 output
  gemm8p<1><<<256, 512, 0, stream>>>(xb, Wb, (void*)outp, midP, Aeff,
                                     4096, 4096, 11008);
}